// Round 2
// baseline (170.907 us; speedup 1.0000x reference)
//
#include <hip/hip_runtime.h>
#include <math.h>

// Problem constants (from reference)
#define NCH 129
#define BS 8
#define TLEN 64000
#define HALF 64           // state granularity AND kC tile length (was 128)
#define NH 1000           // TLEN / HALF
#define LFRM 256          // frame stride
#define NFRM 250          // number of frames
#define NSEQ (NCH * BS)   // 1032 sequences
#define NBK (BS * NFRM)   // 2000 (b,frame) cells
#define NT (BS * NH)      // 8000 (b,tile) cells
#define KA_EDGE 125       // NT/64: kA channel-128 blocks
#define KC_EDGE 32        // ceil(NT/256): kC channel-128 blocks
#define KC_MAIN (NT / 4)  // 2000 main blocks (4 tiles per 256-thr block)
#define GSZ ((size_t)NBK * NCH)   // per-quarter G stride (floats)

// float4 index of state-chunk h, batch b, channel c.  Layout [h][b][c]:
// c fastest -> kA writes (c = tid) and kC reads (c = 2t,2t+1) are coalesced.
#define SEQ4(h, b, c) ((size_t)(h) * NSEQ + (size_t)(b) * NCH + (c))

typedef float f2 __attribute__((ext_vector_type(2)));

__device__ __forceinline__ f2 mk2(float a, float b) { f2 r; r.x = a; r.y = b; return r; }

__device__ __forceinline__ f2 fma2(f2 a, f2 b, f2 c) {
#if __has_builtin(__builtin_elementwise_fma)
    return __builtin_elementwise_fma(a, b, c);
#else
    f2 r; r.x = fmaf(a.x, b.x, c.x); r.y = fmaf(a.y, b.y, c.y); return r;
#endif
}

__device__ __forceinline__ f2 sig2(f2 v) {
    f2 r;
    r.x = __builtin_amdgcn_rcpf(1.0f + __expf(-v.x));
    r.y = __builtin_amdgcn_rcpf(1.0f + __expf(-v.y));
    return r;
}

// Packed pair-of-chains coefficients.
struct C2 { f2 b0, b1, b2, b3, b4, a1, a2, a3, a4; };

__device__ __forceinline__ C2 load_coef2(const float* __restrict__ B,
                                         const float* __restrict__ A,
                                         int cx, int cy) {
    C2 q;
    q.b0 = mk2(B[cx * 5 + 0], B[cy * 5 + 0]);
    q.b1 = mk2(B[cx * 5 + 1], B[cy * 5 + 1]);
    q.b2 = mk2(B[cx * 5 + 2], B[cy * 5 + 2]);
    q.b3 = mk2(B[cx * 5 + 3], B[cy * 5 + 3]);
    q.b4 = mk2(B[cx * 5 + 4], B[cy * 5 + 4]);
    q.a1 = mk2(A[cx * 5 + 1], A[cy * 5 + 1]);
    q.a2 = mk2(A[cx * 5 + 2], A[cy * 5 + 2]);
    q.a3 = mk2(A[cx * 5 + 3], A[cy * 5 + 3]);
    q.a4 = mk2(A[cx * 5 + 4], A[cy * 5 + 4]);
    return q;
}

__device__ __forceinline__ f2 iir2_step(const C2& q, float x,
                                        f2& z0, f2& z1, f2& z2, f2& z3) {
    f2 xx = mk2(x, x);
    f2 y = fma2(q.b0, xx, z0);
    z0 = fma2(-q.a1, y, fma2(q.b1, xx, z1));
    z1 = fma2(-q.a2, y, fma2(q.b2, xx, z2));
    z2 = fma2(-q.a3, y, fma2(q.b3, xx, z3));
    z3 = fma2(-q.a4, y, q.b4 * xx);
    return y;
}

// Scalar variants (kernel A only).
struct Coef { float b0, b1, b2, b3, b4, a1, a2, a3, a4; };
__device__ __forceinline__ Coef load_coef(const float* __restrict__ B,
                                          const float* __restrict__ A, int c) {
    Coef q;
    q.b0 = B[c * 5 + 0]; q.b1 = B[c * 5 + 1]; q.b2 = B[c * 5 + 2];
    q.b3 = B[c * 5 + 3]; q.b4 = B[c * 5 + 4];
    q.a1 = A[c * 5 + 1]; q.a2 = A[c * 5 + 2];
    q.a3 = A[c * 5 + 3]; q.a4 = A[c * 5 + 4];
    return q;
}
__device__ __forceinline__ float iir_step(const Coef& q, float x,
                                          float& z0, float& z1, float& z2, float& z3) {
    float y = fmaf(q.b0, x, z0);
    z0 = fmaf(-q.a1, y, fmaf(q.b1, x, z1));
    z1 = fmaf(-q.a2, y, fmaf(q.b2, x, z2));
    z2 = fmaf(-q.a3, y, fmaf(q.b3, x, z3));
    z3 = fmaf(-q.a4, y, q.b4 * x);
    return y;
}

// step macros for packed chains (coef struct must be named q)
#define WSTEP(xv)                                                              \
    { f2 y_ = iir2_step(q, (xv), z0, z1, z2, z3);                              \
      u = fma2(beta2, u, sig2(y_)); }
#define MSTEP(xv)                                                              \
    { f2 y_ = iir2_step(q, (xv), z0, z1, z2, z3);                              \
      u = fma2(beta2, u, sig2(y_));                                            \
      float un_ = __shfl_down(u.x, 1, 64);                                     \
      float y4o_ = fmaxf(u.y - u.x, 0.0f);                                     \
      float y4e_ = fmaxf(pend_un - pend_ub, 0.0f);                             \
      g2 = fma2(alpha2, g2, mk2(y4o_, y4e_));                                  \
      pend_un = un_; pend_ub = u.y; }

// ---- 4x4 matrix helpers over 16 NAMED scalars (no arrays -> no scratch) ----
#define MDECL(X) float X##00, X##01, X##02, X##03, X##10, X##11, X##12, X##13, \
                       X##20, X##21, X##22, X##23, X##30, X##31, X##32, X##33
#define MCOPY(D, S) D##00=S##00; D##01=S##01; D##02=S##02; D##03=S##03;        \
                    D##10=S##10; D##11=S##11; D##12=S##12; D##13=S##13;        \
                    D##20=S##20; D##21=S##21; D##22=S##22; D##23=S##23;        \
                    D##30=S##30; D##31=S##31; D##32=S##32; D##33=S##33
#define MROW(R, X, Y, i)                                                       \
    R##i##0 = fmaf(X##i##0, Y##00, fmaf(X##i##1, Y##10, fmaf(X##i##2, Y##20, X##i##3 * Y##30))); \
    R##i##1 = fmaf(X##i##0, Y##01, fmaf(X##i##1, Y##11, fmaf(X##i##2, Y##21, X##i##3 * Y##31))); \
    R##i##2 = fmaf(X##i##0, Y##02, fmaf(X##i##1, Y##12, fmaf(X##i##2, Y##22, X##i##3 * Y##32))); \
    R##i##3 = fmaf(X##i##0, Y##03, fmaf(X##i##1, Y##13, fmaf(X##i##2, Y##23, X##i##3 * Y##33)))
#define MMUL(R, X, Y) MROW(R, X, Y, 0); MROW(R, X, Y, 1); MROW(R, X, Y, 2); MROW(R, X, Y, 3)
// r (float4) = X * v (float4)
#define MV(r, X, v)                                                            \
    r.x = fmaf(X##00, v.x, fmaf(X##01, v.y, fmaf(X##02, v.z, X##03 * v.w)));   \
    r.y = fmaf(X##10, v.x, fmaf(X##11, v.y, fmaf(X##12, v.z, X##13 * v.w)));   \
    r.z = fmaf(X##20, v.x, fmaf(X##21, v.y, fmaf(X##22, v.z, X##23 * v.w)));   \
    r.w = fmaf(X##30, v.x, fmaf(X##31, v.y, fmaf(X##32, v.z, X##33 * v.w)))

// ---------------------------------------------------------------------------
// Kernel A: forced-response state per (c, b, 64-chunk h), zero initial state.
// Blocks [0, KA_EDGE): channel 128 — one (b,h) item per lane.
// Blocks [KA_EDGE, +NT): channels 0..127 — 128 threads, LDS-staged x.
// zs[h][b][c] float4; after kB it holds the exact state at sample 64h.
// ---------------------------------------------------------------------------
__global__ __launch_bounds__(128, 8) void kA_forced_state(
        const float* __restrict__ wav, const float* __restrict__ B,
        const float* __restrict__ A, float* __restrict__ zs) {
    __shared__ float xs[HALF];
    int blk = blockIdx.x;
    if (blk < KA_EDGE) {
        int item = blk * 64 + threadIdx.x;   // only wave 0 does work
        if (threadIdx.x >= 64 || item >= NT) return;
        int b = item / NH;
        int h = item - b * NH;
        const float* xg = wav + (size_t)b * TLEN + (size_t)h * HALF;
        Coef q = load_coef(B, A, 128);
        float z0 = 0.f, z1 = 0.f, z2 = 0.f, z3 = 0.f;
        #pragma unroll 4
        for (int j = 0; j < HALF; ++j) {
            (void)iir_step(q, xg[j], z0, z1, z2, z3);
        }
        ((float4*)zs)[SEQ4(h, b, 128)] = make_float4(z0, z1, z2, z3);
        return;
    }
    int mblk = blk - KA_EDGE;        // b * NH + h
    int b = mblk / NH;
    int h = mblk - b * NH;
    const float* xg = wav + (size_t)b * TLEN + (size_t)h * HALF;
    if (threadIdx.x < HALF) xs[threadIdx.x] = xg[threadIdx.x];
    __syncthreads();
    int c = threadIdx.x;             // 0..127
    Coef q = load_coef(B, A, c);
    float z0 = 0.f, z1 = 0.f, z2 = 0.f, z3 = 0.f;
    #pragma unroll 8
    for (int j = 0; j < HALF; ++j) {
        (void)iir_step(q, xs[j], z0, z1, z2, z3);
    }
    ((float4*)zs)[SEQ4(h, b, c)] = make_float4(z0, z1, z2, z3);  // coalesced in c
}

// ---------------------------------------------------------------------------
// Kernel B: PARALLEL exclusive scan of 64-chunk states. One wave per (c,b).
// Lane l owns h in [16l, 16l+16) (1024 >= NH=1000, padded with d=0).
//   z_in[h] = M64 * z_in[h-1] + d[h-1],  z_in[0] = 0.
// Phase 1: lane folds its 16 d's. Phase 2: Kogge-Stone with P = M64^16.
// Phase 3: exclusive shift. Phase 4: replay 16 local steps, store (guarded).
// ---------------------------------------------------------------------------
#define KB_LOAD(dn, i)                                                         \
    {   int hh = h0 + (i); int hcl = (hh < NH) ? hh : (NH - 1);                \
        dn = zb[SEQ4(hcl, b, c)];                                              \
        if (hh >= NH) dn = make_float4(0.f, 0.f, 0.f, 0.f); }
#define KB_FOLD(dn)                                                            \
    {   float4 t_; MV(t_, M1, e);                                              \
        e.x = t_.x + dn.x; e.y = t_.y + dn.y;                                  \
        e.z = t_.z + dn.z; e.w = t_.w + dn.w; }
#define KB_REPLAY(dn, i)                                                       \
    {   int hh = h0 + (i);                                                     \
        if (hh < NH) zbw[SEQ4(hh, b, c)] = zz;                                 \
        float4 t_; MV(t_, M1, zz);                                             \
        zz.x = t_.x + dn.x; zz.y = t_.y + dn.y;                                \
        zz.z = t_.z + dn.z; zz.w = t_.w + dn.w; }

__global__ __launch_bounds__(256) void kB_scan_par(
        const float* __restrict__ A, float* __restrict__ zs) {
    int id = blockIdx.x * 4 + (threadIdx.x >> 6);   // sequence c*BS+b
    int lane = threadIdx.x & 63;
    if (id >= NSEQ) return;
    int c = id / BS;
    int b = id - c * BS;
    float a1 = A[c * 5 + 1], a2 = A[c * 5 + 2], a3 = A[c * 5 + 3], a4 = A[c * 5 + 4];
    // companion matrix M -> M1 = M^64 via 6 squarings
    MDECL(M1);
    M100 = -a1; M101 = 1.f; M102 = 0.f; M103 = 0.f;
    M110 = -a2; M111 = 0.f; M112 = 1.f; M113 = 0.f;
    M120 = -a3; M121 = 0.f; M122 = 0.f; M123 = 1.f;
    M130 = -a4; M131 = 0.f; M132 = 0.f; M133 = 0.f;
    for (int s = 0; s < 6; ++s) {
        MDECL(T); MMUL(T, M1, M1); MCOPY(M1, T);
    }
    // P = M64^16 (segment transform) via 4 squarings
    MDECL(P);
    MCOPY(P, M1);
    for (int s = 0; s < 4; ++s) {
        MDECL(T); MMUL(T, P, P); MCOPY(P, T);
    }

    const float4* zb = (const float4*)zs;
    float4* zbw = (float4*)zs;
    int h0 = lane * 16;
    float4 d0, d1, d2, d3, d4, d5, d6, d7, d8, d9, d10, d11, d12, d13, d14, d15;
    KB_LOAD(d0, 0);  KB_LOAD(d1, 1);  KB_LOAD(d2, 2);  KB_LOAD(d3, 3);
    KB_LOAD(d4, 4);  KB_LOAD(d5, 5);  KB_LOAD(d6, 6);  KB_LOAD(d7, 7);
    KB_LOAD(d8, 8);  KB_LOAD(d9, 9);  KB_LOAD(d10, 10); KB_LOAD(d11, 11);
    KB_LOAD(d12, 12); KB_LOAD(d13, 13); KB_LOAD(d14, 14); KB_LOAD(d15, 15);

    // Phase 1: fold
    float4 e = d0;
    KB_FOLD(d1);  KB_FOLD(d2);  KB_FOLD(d3);  KB_FOLD(d4);
    KB_FOLD(d5);  KB_FOLD(d6);  KB_FOLD(d7);  KB_FOLD(d8);
    KB_FOLD(d9);  KB_FOLD(d10); KB_FOLD(d11); KB_FOLD(d12);
    KB_FOLD(d13); KB_FOLD(d14); KB_FOLD(d15);

    // Phase 2: Kogge-Stone, uniform matrix power P = (M64^16)^{2^s}
    for (int s = 0; s < 6; ++s) {
        int off = 1 << s;
        float4 src;
        src.x = __shfl_up(e.x, off, 64);
        src.y = __shfl_up(e.y, off, 64);
        src.z = __shfl_up(e.z, off, 64);
        src.w = __shfl_up(e.w, off, 64);
        if (lane < off) { src.x = 0.f; src.y = 0.f; src.z = 0.f; src.w = 0.f; }
        float4 t_; MV(t_, P, src);
        e.x += t_.x; e.y += t_.y; e.z += t_.z; e.w += t_.w;
        if (s < 5) { MDECL(T); MMUL(T, P, P); MCOPY(P, T); }
    }

    // Phase 3: exclusive shift
    float4 zz;
    zz.x = __shfl_up(e.x, 1, 64);
    zz.y = __shfl_up(e.y, 1, 64);
    zz.z = __shfl_up(e.z, 1, 64);
    zz.w = __shfl_up(e.w, 1, 64);
    if (lane == 0) { zz.x = 0.f; zz.y = 0.f; zz.z = 0.f; zz.w = 0.f; }

    // Phase 4: replay + store
    KB_REPLAY(d0, 0);  KB_REPLAY(d1, 1);  KB_REPLAY(d2, 2);  KB_REPLAY(d3, 3);
    KB_REPLAY(d4, 4);  KB_REPLAY(d5, 5);  KB_REPLAY(d6, 6);  KB_REPLAY(d7, 7);
    KB_REPLAY(d8, 8);  KB_REPLAY(d9, 9);  KB_REPLAY(d10, 10); KB_REPLAY(d11, 11);
    KB_REPLAY(d12, 12); KB_REPLAY(d13, 13); KB_REPLAY(d14, 14); KB_REPLAY(d15, 15);
}

// ---------------------------------------------------------------------------
// Kernel C: 64-sample tiles, 256-thr blocks (4 tiles/block, per-wave LDS).
// Tile r in [0, NH) covers samples [64r, 64r+64); frame k = r>>2,
// quarter qd = r&3. Warm-up over [64(r-1), 64r) from the EXACT state
// zs[r-1]: 64 full WSTEPs (beta^64 = 3.4e-4 truncation, same as before).
// Each quarter emits Gq (and y4f for qd==0); kD combines 4 quarters.
// Blocks [0, KC_EDGE): channel-128 path, one (b,r) item per thread.
// Blocks [KC_EDGE, +KC_MAIN): pair-channel main, wave w -> tile blk*4+w;
// lane t runs packed chains {2t,2t+1}; shfl consumed one step late.
// 8000 tiles -> ~7.9 blocks/CU -> ~31 waves/CU (VGPR=40 permits), vs 16
// waves/CU at HALF=128: the occupancy doubling is the point of this round.
// ---------------------------------------------------------------------------
__global__ __launch_bounds__(256, 8) void kC_main(
        const float* __restrict__ wav, const float* __restrict__ B,
        const float* __restrict__ A, const float* __restrict__ zs,
        float* __restrict__ G, float* __restrict__ y4f,
        float beta, float alpha) {
    __shared__ float4 xs4[4 * 32];   // per-wave 32-float4 segments
    int blk = blockIdx.x;
    const f2 beta2 = mk2(beta, beta);
    const f2 alpha2 = mk2(alpha, alpha);

    if (blk < KC_EDGE) {
        // ---- edge: channel 128, one (b,r) per thread ----
        int item = blk * 256 + threadIdx.x;
        if (item >= NT) return;
        int b = item / NH;
        int r = item - b * NH;
        int k = r >> 2, qd = r & 3;
        C2 q = load_coef2(B, A, 127, 128);
        f2 z0 = mk2(0.f, 0.f), z1 = z0, z2 = z0, z3 = z0, u = z0;
        const float* xg;
        if (r > 0) {
            float4 vx = ((const float4*)zs)[SEQ4(r - 1, b, 127)];
            float4 vy = ((const float4*)zs)[SEQ4(r - 1, b, 128)];
            z0 = mk2(vx.x, vy.x); z1 = mk2(vx.y, vy.y);
            z2 = mk2(vx.z, vy.z); z3 = mk2(vx.w, vy.w);
            xg = wav + (size_t)b * TLEN + (size_t)(r - 1) * HALF;
            #pragma unroll 2
            for (int j = 0; j < HALF; ++j) WSTEP(xg[j]);
            xg += HALF;
        } else {
            xg = wav + (size_t)b * TLEN;
        }
        float g4 = 0.f, yfirst = 0.f;
        #pragma unroll 2
        for (int j = 0; j < HALF; ++j) {
            f2 y_ = iir2_step(q, xg[j], z0, z1, z2, z3);
            u = fma2(beta2, u, sig2(y_));
            float y4 = fmaxf(u.y - u.x, 0.0f);   // ch128 - ch127
            if (j == 0) yfirst = y4;
            g4 = fmaf(alpha, g4, y4);
        }
        size_t idx = ((size_t)b * NFRM + k) * NCH + 128;
        G[(size_t)qd * GSZ + idx] = g4;
        if (qd == 0) y4f[idx] = yfirst;
        return;
    }

    // ---- main: wave w handles tile (blk-KC_EDGE)*4 + w ----
    int wave = threadIdx.x >> 6;
    int t = threadIdx.x & 63;                // lane 0..63
    int tile = (blk - KC_EDGE) * 4 + wave;   // b * NH + r, < NT
    int b = tile / NH;
    int r = tile - b * NH;
    int k = r >> 2, qd = r & 3;
    int n4 = (r > 0) ? 32 : 16;
    const float* xg = wav + (size_t)b * TLEN +
                      ((r > 0) ? (size_t)(r - 1) * HALF : (size_t)0);
    float4* seg = xs4 + wave * 32;
    if (t < n4) seg[t] = ((const float4*)xg)[t];
    __syncthreads();

    int cA = 2 * t, cB = 2 * t + 1;          // chains (cB <= 127)
    C2 q = load_coef2(B, A, cA, cB);
    f2 z0 = mk2(0.f, 0.f), z1 = z0, z2 = z0, z3 = z0, u = z0;
    int gbase = 0;
    if (r > 0) {
        // coalesced: wave reads c = 0..127 consecutive float4s
        float4 vx = ((const float4*)zs)[SEQ4(r - 1, b, cA)];
        float4 vy = ((const float4*)zs)[SEQ4(r - 1, b, cB)];
        z0 = mk2(vx.x, vy.x); z1 = mk2(vx.y, vy.y);
        z2 = mk2(vx.z, vy.z); z3 = mk2(vx.w, vy.w);
        for (int g = 0; g < HALF / 4; ++g) {       // 64 steps full warm
            float4 xq = seg[g];
            WSTEP(xq.x); WSTEP(xq.y); WSTEP(xq.z); WSTEP(xq.w);
        }
        gbase = HALF / 4;
    }

    // main 64 steps; pipeline: ge consumes shfl one step late.
    f2 g2;
    float fo, fe, pend_un, pend_ub;
    {   // first group: peel j=0 and j=1
        float4 xq = seg[gbase];
        // j = 0
        f2 y_ = iir2_step(q, xq.x, z0, z1, z2, z3);
        u = fma2(beta2, u, sig2(y_));
        float un_ = __shfl_down(u.x, 1, 64);
        float y4o_ = fmaxf(u.y - u.x, 0.0f);
        fo = y4o_;
        g2 = mk2(y4o_, 0.0f);
        pend_un = un_; pend_ub = u.y;
        // j = 1
        y_ = iir2_step(q, xq.y, z0, z1, z2, z3);
        u = fma2(beta2, u, sig2(y_));
        un_ = __shfl_down(u.x, 1, 64);
        y4o_ = fmaxf(u.y - u.x, 0.0f);
        float y4e_ = fmaxf(pend_un - pend_ub, 0.0f);
        fe = y4e_;                            // y4e at j=0
        g2 = fma2(alpha2, g2, mk2(y4o_, y4e_));
        pend_un = un_; pend_ub = u.y;
        // j = 2, 3
        MSTEP(xq.z); MSTEP(xq.w);
    }
    for (int g = gbase + 1; g < gbase + HALF / 4; ++g) {
        float4 xq = seg[g];
        MSTEP(xq.x); MSTEP(xq.y); MSTEP(xq.z); MSTEP(xq.w);
    }
    // tail: apply the last pending ge term
    float y4e_last = fmaxf(pend_un - pend_ub, 0.0f);
    float go = g2.x;
    float ge = fmaf(alpha, g2.y, y4e_last);

    size_t base = ((size_t)b * NFRM + k) * NCH;
    float* Gq = G + (size_t)qd * GSZ;
    if (qd == 0) {
        Gq[base + cB] = go;            // channel 2t+1 (odd 1..127)
        y4f[base + cB] = fo;
        if (t < 63) {
            Gq[base + cB + 1] = ge;    // channel 2t+2 (even 2..126)
            y4f[base + cB + 1] = fe;
        }
    } else {
        Gq[base + cB] = go;
        if (t < 63) Gq[base + cB + 1] = ge;
    }
}

// ---------------------------------------------------------------------------
// Kernel D: PARALLEL alpha-scan per (b,c) — one wave per sequence.
// Lane l owns frames [4l, 4l+4) (256 >= NFRM=250, padded g=0).
//   o[k] = alpha * s_in[k] + y4f[k];  s' = aL*s + g,
//   g = ((G0*aH + G1)*aH + G2)*aH + G3,  aH = alpha^64, aL = alpha^256.
// ---------------------------------------------------------------------------
#define KD_LOAD(gn, yn, i)                                                     \
    {   int kk = k0 + (i); int kcl = (kk < NFRM) ? kk : (NFRM - 1);            \
        size_t ix = ((size_t)b * NFRM + kcl) * NCH + c;                        \
        gn = fmaf(aH, fmaf(aH, fmaf(aH, G[ix], G[GSZ + ix]),                   \
                           G[2 * GSZ + ix]), G[3 * GSZ + ix]);                 \
        yn = y4f[ix];                                                          \
        if (kk >= NFRM) { gn = 0.f; yn = 0.f; } }
#define KD_REPLAY(gn, yn, i)                                                   \
    {   int kk = k0 + (i);                                                     \
        if (kk < NFRM) o[kk] = fmaf(alpha, sv, yn);                            \
        sv = fmaf(aL, sv, gn); }

__global__ __launch_bounds__(256) void kD_scan_par(
        const float* __restrict__ G, const float* __restrict__ y4f,
        float* __restrict__ out, float alpha, float aL, float aH) {
    int id = blockIdx.x * 4 + (threadIdx.x >> 6);   // b * NCH + c
    int lane = threadIdx.x & 63;
    if (id >= NSEQ) return;
    int b = id / NCH;
    int c = id - b * NCH;
    float* o = out + (size_t)id * NFRM;
    int k0 = lane * 4;
    if (c == 0) {
        #pragma unroll
        for (int i = 0; i < 4; ++i) {
            int kk = k0 + i;
            if (kk < NFRM) o[kk] = 0.0f;
        }
        return;
    }
    float g0, g1, g2v, g3, y0, y1, y2v, y3;
    KD_LOAD(g0, y0, 0); KD_LOAD(g1, y1, 1); KD_LOAD(g2v, y2v, 2); KD_LOAD(g3, y3, 3);
    // local inclusive carry
    float e = g0;
    e = fmaf(aL, e, g1);
    e = fmaf(aL, e, g2v);
    e = fmaf(aL, e, g3);
    // Kogge-Stone with factor f = (aL^4)^{2^s}
    float aL2 = aL * aL;
    float f = aL2 * aL2;                     // aL^4
    for (int s = 0; s < 6; ++s) {
        int off = 1 << s;
        float src = __shfl_up(e, off, 64);
        if (lane < off) src = 0.f;
        e = fmaf(f, src, e);
        f = f * f;
    }
    // exclusive shift
    float sv = __shfl_up(e, 1, 64);
    if (lane == 0) sv = 0.f;
    // replay + store
    KD_REPLAY(g0, y0, 0); KD_REPLAY(g1, y1, 1);
    KD_REPLAY(g2v, y2v, 2); KD_REPLAY(g3, y3, 3);
}

// ---------------------------------------------------------------------------
extern "C" void kernel_launch(void* const* d_in, const int* in_sizes, int n_in,
                              void* d_out, int out_size, void* d_ws, size_t ws_size,
                              hipStream_t stream) {
    const float* wav = (const float*)d_in[0];   // (BS, TLEN)
    const float* Bc  = (const float*)d_in[1];   // (NCH, 5)
    const float* Ac  = (const float*)d_in[2];   // (NCH, 5)
    float* out = (float*)d_out;                 // (BS, NCH, NFRM)

    // workspace: zs (NH*NSEQ float4 = 16.5 MB) | G (4 quarters, 4.13 MB) |
    //            y4f (1.03 MB)
    float* zs  = (float*)d_ws;
    float* G   = zs + (size_t)NH * NSEQ * 4;
    float* y4f = G + 4 * GSZ;

    const float alpha  = (float)exp(-1.0 / 128.0);
    const float beta   = (float)exp(-1.0 / 8.0);
    const float alphaL = (float)exp(-256.0 / 128.0);   // alpha^256 (frame step)
    const float alphaH = (float)exp(-64.0 / 128.0);    // alpha^64 (quarter step)

    kA_forced_state<<<KA_EDGE + NT, 128, 0, stream>>>(wav, Bc, Ac, zs);
    kB_scan_par<<<NSEQ / 4, 256, 0, stream>>>(Ac, zs);
    kC_main<<<KC_EDGE + KC_MAIN, 256, 0, stream>>>(wav, Bc, Ac, zs, G, y4f, beta, alpha);
    kD_scan_par<<<NSEQ / 4, 256, 0, stream>>>(G, y4f, out, alpha, alphaL, alphaH);
}

// Round 3
// 142.712 us; speedup vs baseline: 1.1976x; 1.1976x over previous
//
#include <hip/hip_runtime.h>
#include <math.h>

// Problem constants (from reference)
#define NCH 129
#define BS 8
#define TLEN 64000
#define CHUNK 64          // state granularity (zs every 64 samples)
#define NH 1000           // TLEN / CHUNK state chunks
#define TILE 128          // kC tile length (one frame half)
#define NHT 500           // TLEN / TILE tiles per sequence-batch
#define LFRM 256          // frame stride
#define NFRM 250          // number of frames
#define NSEQ (NCH * BS)   // 1032 sequences
#define NBK (BS * NFRM)   // 2000 (b,frame) cells
#define NT (BS * NH)      // 8000 (b,chunk) items (kernel A)
#define NTC (BS * NHT)    // 4000 (b,tile) items (kernel C)
#define KA_EDGE 63        // ceil(NT/128): kA channel-128 blocks
#define KC_EDGE 16        // ceil(NTC/256): kC channel-128 blocks
#define KC_MAIN (NTC / 4) // 1000 main blocks (4 tiles per 256-thr block)
#define SEG 40            // kB segments
#define LSEG 25           // chunks per segment (SEG*LSEG == NH)
#define SGRP 17           // ceil(NSEQ/64) sequence groups per segment

// float4 index of state-chunk h, batch b, channel c.  Layout [h][b][c]:
// c fastest -> kA writes (c = tid) and kC reads (c = 2t,2t+1) are coalesced.
#define SEQ4(h, b, c) ((size_t)(h) * NSEQ + (size_t)(b) * NCH + (c))

typedef float f2 __attribute__((ext_vector_type(2)));

__device__ __forceinline__ f2 mk2(float a, float b) { f2 r; r.x = a; r.y = b; return r; }

__device__ __forceinline__ f2 fma2(f2 a, f2 b, f2 c) {
#if __has_builtin(__builtin_elementwise_fma)
    return __builtin_elementwise_fma(a, b, c);
#else
    f2 r; r.x = fmaf(a.x, b.x, c.x); r.y = fmaf(a.y, b.y, c.y); return r;
#endif
}

__device__ __forceinline__ f2 sig2(f2 v) {
    f2 r;
    r.x = __builtin_amdgcn_rcpf(1.0f + __expf(-v.x));
    r.y = __builtin_amdgcn_rcpf(1.0f + __expf(-v.y));
    return r;
}

// Packed pair-of-chains coefficients.
struct C2 { f2 b0, b1, b2, b3, b4, a1, a2, a3, a4; };

__device__ __forceinline__ C2 load_coef2(const float* __restrict__ B,
                                         const float* __restrict__ A,
                                         int cx, int cy) {
    C2 q;
    q.b0 = mk2(B[cx * 5 + 0], B[cy * 5 + 0]);
    q.b1 = mk2(B[cx * 5 + 1], B[cy * 5 + 1]);
    q.b2 = mk2(B[cx * 5 + 2], B[cy * 5 + 2]);
    q.b3 = mk2(B[cx * 5 + 3], B[cy * 5 + 3]);
    q.b4 = mk2(B[cx * 5 + 4], B[cy * 5 + 4]);
    q.a1 = mk2(A[cx * 5 + 1], A[cy * 5 + 1]);
    q.a2 = mk2(A[cx * 5 + 2], A[cy * 5 + 2]);
    q.a3 = mk2(A[cx * 5 + 3], A[cy * 5 + 3]);
    q.a4 = mk2(A[cx * 5 + 4], A[cy * 5 + 4]);
    return q;
}

__device__ __forceinline__ f2 iir2_step(const C2& q, float x,
                                        f2& z0, f2& z1, f2& z2, f2& z3) {
    f2 xx = mk2(x, x);
    f2 y = fma2(q.b0, xx, z0);
    z0 = fma2(-q.a1, y, fma2(q.b1, xx, z1));
    z1 = fma2(-q.a2, y, fma2(q.b2, xx, z2));
    z2 = fma2(-q.a3, y, fma2(q.b3, xx, z3));
    z3 = fma2(-q.a4, y, q.b4 * xx);
    return y;
}

// Scalar variants (kernel A only).
struct Coef { float b0, b1, b2, b3, b4, a1, a2, a3, a4; };
__device__ __forceinline__ Coef load_coef(const float* __restrict__ B,
                                          const float* __restrict__ A, int c) {
    Coef q;
    q.b0 = B[c * 5 + 0]; q.b1 = B[c * 5 + 1]; q.b2 = B[c * 5 + 2];
    q.b3 = B[c * 5 + 3]; q.b4 = B[c * 5 + 4];
    q.a1 = A[c * 5 + 1]; q.a2 = A[c * 5 + 2];
    q.a3 = A[c * 5 + 3]; q.a4 = A[c * 5 + 4];
    return q;
}
__device__ __forceinline__ float iir_step(const Coef& q, float x,
                                          float& z0, float& z1, float& z2, float& z3) {
    float y = fmaf(q.b0, x, z0);
    z0 = fmaf(-q.a1, y, fmaf(q.b1, x, z1));
    z1 = fmaf(-q.a2, y, fmaf(q.b2, x, z2));
    z2 = fmaf(-q.a3, y, fmaf(q.b3, x, z3));
    z3 = fmaf(-q.a4, y, q.b4 * x);
    return y;
}

// step macros for packed chains (coef struct must be named q)
#define WSTEP(xv)                                                              \
    { f2 y_ = iir2_step(q, (xv), z0, z1, z2, z3);                              \
      u = fma2(beta2, u, sig2(y_)); }
#define MSTEP(xv)                                                              \
    { f2 y_ = iir2_step(q, (xv), z0, z1, z2, z3);                              \
      u = fma2(beta2, u, sig2(y_));                                            \
      float un_ = __shfl_down(u.x, 1, 64);                                     \
      float y4o_ = fmaxf(u.y - u.x, 0.0f);                                     \
      float y4e_ = fmaxf(pend_un - pend_ub, 0.0f);                             \
      g2 = fma2(alpha2, g2, mk2(y4o_, y4e_));                                  \
      pend_un = un_; pend_ub = u.y; }

// ---- 4x4 matrix helpers over 16 NAMED scalars (no arrays -> no scratch) ----
#define MDECL(X) float X##00, X##01, X##02, X##03, X##10, X##11, X##12, X##13, \
                       X##20, X##21, X##22, X##23, X##30, X##31, X##32, X##33
#define MCOPY(D, S) D##00=S##00; D##01=S##01; D##02=S##02; D##03=S##03;        \
                    D##10=S##10; D##11=S##11; D##12=S##12; D##13=S##13;        \
                    D##20=S##20; D##21=S##21; D##22=S##22; D##23=S##23;        \
                    D##30=S##30; D##31=S##31; D##32=S##32; D##33=S##33
#define MROW(R, X, Y, i)                                                       \
    R##i##0 = fmaf(X##i##0, Y##00, fmaf(X##i##1, Y##10, fmaf(X##i##2, Y##20, X##i##3 * Y##30))); \
    R##i##1 = fmaf(X##i##0, Y##01, fmaf(X##i##1, Y##11, fmaf(X##i##2, Y##21, X##i##3 * Y##31))); \
    R##i##2 = fmaf(X##i##0, Y##02, fmaf(X##i##1, Y##12, fmaf(X##i##2, Y##22, X##i##3 * Y##32))); \
    R##i##3 = fmaf(X##i##0, Y##03, fmaf(X##i##1, Y##13, fmaf(X##i##2, Y##23, X##i##3 * Y##33)))
#define MMUL(R, X, Y) MROW(R, X, Y, 0); MROW(R, X, Y, 1); MROW(R, X, Y, 2); MROW(R, X, Y, 3)
// r (float4) = X * v (float4)
#define MV(r, X, v)                                                            \
    r.x = fmaf(X##00, v.x, fmaf(X##01, v.y, fmaf(X##02, v.z, X##03 * v.w)));   \
    r.y = fmaf(X##10, v.x, fmaf(X##11, v.y, fmaf(X##12, v.z, X##13 * v.w)));   \
    r.z = fmaf(X##20, v.x, fmaf(X##21, v.y, fmaf(X##22, v.z, X##23 * v.w)));   \
    r.w = fmaf(X##30, v.x, fmaf(X##31, v.y, fmaf(X##32, v.z, X##33 * v.w)))
// build companion matrix M and raise to M^64 (6 squarings)
#define BUILD_M64(M1, a1, a2, a3, a4)                                          \
    M1##00 = -(a1); M1##01 = 1.f; M1##02 = 0.f; M1##03 = 0.f;                  \
    M1##10 = -(a2); M1##11 = 0.f; M1##12 = 1.f; M1##13 = 0.f;                  \
    M1##20 = -(a3); M1##21 = 0.f; M1##22 = 0.f; M1##23 = 1.f;                  \
    M1##30 = -(a4); M1##31 = 0.f; M1##32 = 0.f; M1##33 = 0.f;                  \
    for (int s_ = 0; s_ < 6; ++s_) { MDECL(T_); MMUL(T_, M1, M1); MCOPY(M1, T_); }

// affine step helper: e = M*e + d
#define AFF_STEP(M, e, d)                                                      \
    {   float4 t_; MV(t_, M, e);                                               \
        e.x = t_.x + d.x; e.y = t_.y + d.y;                                    \
        e.z = t_.z + d.z; e.w = t_.w + d.w; }

// ---------------------------------------------------------------------------
// Kernel A: forced-response state per (c, b, 64-chunk h), zero initial state.
// Blocks [0, KA_EDGE): channel 128 — one (b,h) item per thread (128/block).
// Blocks [KA_EDGE, +NT): channels 0..127 — 128 threads, LDS-staged x.
// zs[h][b][c] float4 = forced response d[h] (chunk from zero state).
// ---------------------------------------------------------------------------
__global__ __launch_bounds__(128, 8) void kA_forced_state(
        const float* __restrict__ wav, const float* __restrict__ B,
        const float* __restrict__ A, float* __restrict__ zs) {
    __shared__ float xs[CHUNK];
    int blk = blockIdx.x;
    if (blk < KA_EDGE) {
        int item = blk * 128 + threadIdx.x;
        if (item >= NT) return;
        int b = item / NH;
        int h = item - b * NH;
        const float* xg = wav + (size_t)b * TLEN + (size_t)h * CHUNK;
        Coef q = load_coef(B, A, 128);
        float z0 = 0.f, z1 = 0.f, z2 = 0.f, z3 = 0.f;
        #pragma unroll 4
        for (int j = 0; j < CHUNK; ++j) {
            (void)iir_step(q, xg[j], z0, z1, z2, z3);
        }
        ((float4*)zs)[SEQ4(h, b, 128)] = make_float4(z0, z1, z2, z3);
        return;
    }
    int mblk = blk - KA_EDGE;        // b * NH + h
    int b = mblk / NH;
    int h = mblk - b * NH;
    const float* xg = wav + (size_t)b * TLEN + (size_t)h * CHUNK;
    if (threadIdx.x < CHUNK) xs[threadIdx.x] = xg[threadIdx.x];
    __syncthreads();
    int c = threadIdx.x;             // 0..127
    Coef q = load_coef(B, A, c);
    float z0 = 0.f, z1 = 0.f, z2 = 0.f, z3 = 0.f;
    #pragma unroll 8
    for (int j = 0; j < CHUNK; ++j) {
        (void)iir_step(q, xs[j], z0, z1, z2, z3);
    }
    ((float4*)zs)[SEQ4(h, b, c)] = make_float4(z0, z1, z2, z3);  // coalesced in c
}

// ---------------------------------------------------------------------------
// Kernel B (3-pass segmented affine scan, lane-coalesced).
// Sequence id s = b*NCH + c in [0,NSEQ); lanes span consecutive s so every
// zs access is a contiguous 1 KB wave transaction (vs 16.5 KB lane strides
// of the old Kogge-Stone-over-h kB, which was the R2 regression).
// kB1: per (seg, s): E[seg][s] = forced response of segment (fold 25 d's).
// kB2: per s: serial scan over 40 segment carries with ML = M64^25;
//      overwrites E[seg][s] with the EXCLUSIVE segment-start state.
// kB3: per (seg, s): replay 25 chunks from start state, writing exact
//      state into zs[h] for ODD h only (the only states kC reads).
// ---------------------------------------------------------------------------
__global__ __launch_bounds__(64) void kB1_fold(
        const float* __restrict__ A, const float* __restrict__ zs,
        float* __restrict__ E) {
    int seg = blockIdx.x / SGRP;
    int s = (blockIdx.x % SGRP) * 64 + threadIdx.x;
    if (s >= NSEQ) return;
    int c = s % NCH;
    float a1 = A[c * 5 + 1], a2 = A[c * 5 + 2], a3 = A[c * 5 + 3], a4 = A[c * 5 + 4];
    MDECL(M1); BUILD_M64(M1, a1, a2, a3, a4);
    const float4* zb = (const float4*)zs;
    float4 e = make_float4(0.f, 0.f, 0.f, 0.f);
    size_t base = (size_t)seg * LSEG * NSEQ + s;
    #pragma unroll 5
    for (int i = 0; i < LSEG; ++i) {
        float4 d = zb[base + (size_t)i * NSEQ];
        AFF_STEP(M1, e, d);
    }
    ((float4*)E)[(size_t)seg * NSEQ + s] = e;
}

__global__ __launch_bounds__(64) void kB2_carry(
        const float* __restrict__ A, float* __restrict__ E) {
    int s = blockIdx.x * 64 + threadIdx.x;
    if (s >= NSEQ) return;
    int c = s % NCH;
    float a1 = A[c * 5 + 1], a2 = A[c * 5 + 2], a3 = A[c * 5 + 3], a4 = A[c * 5 + 4];
    MDECL(M1); BUILD_M64(M1, a1, a2, a3, a4);
    // ML = M1^25 = M1^16 * M1^8 * M1
    MDECL(P8);
    { MDECL(T); MMUL(T, M1, M1); MDECL(P4); MMUL(P4, T, T); MMUL(P8, P4, P4); }
    MDECL(ML);
    { MDECL(P16); MMUL(P16, P8, P8); MDECL(P24); MMUL(P24, P16, P8);
      MMUL(ML, P24, M1); }
    float4* E4 = (float4*)E;
    float4 Z = make_float4(0.f, 0.f, 0.f, 0.f);
    for (int seg = 0; seg < SEG; ++seg) {
        size_t ix = (size_t)seg * NSEQ + s;
        float4 Eseg = E4[ix];
        E4[ix] = Z;                  // exclusive segment-start state
        AFF_STEP(ML, Z, Eseg);
    }
}

__global__ __launch_bounds__(64) void kB3_replay(
        const float* __restrict__ A, float* __restrict__ zs,
        const float* __restrict__ E) {
    int seg = blockIdx.x / SGRP;
    int s = (blockIdx.x % SGRP) * 64 + threadIdx.x;
    if (s >= NSEQ) return;
    int c = s % NCH;
    float a1 = A[c * 5 + 1], a2 = A[c * 5 + 2], a3 = A[c * 5 + 3], a4 = A[c * 5 + 4];
    MDECL(M1); BUILD_M64(M1, a1, a2, a3, a4);
    float4* zb = (float4*)zs;
    float4 z = ((const float4*)E)[(size_t)seg * NSEQ + s];
    int h0 = seg * LSEG;
    #pragma unroll 5
    for (int i = 0; i < LSEG; ++i) {
        size_t ix = (size_t)(h0 + i) * NSEQ + s;
        float4 d = zb[ix];           // read forced response BEFORE overwrite
        if ((h0 + i) & 1) zb[ix] = z;  // exact state; only odd h consumed
        AFF_STEP(M1, z, d);
    }
}

// ---------------------------------------------------------------------------
// Kernel C: 128-sample frame-half tiles, 256-thr blocks (4 tiles/block).
// Tile r in [0, NHT) covers samples [128r, 128r+128); frame k = r>>1,
// half = r&1. Warm-up: only 64 WSTEPs over [128r-64, 128r) from the EXACT
// state zs[2r-1] (beta^64 = 3.4e-4 u-truncation, z exact — identical math
// to R1 but 64 fewer steps/tile: 192 vs 256 steps per 128 outputs).
// Blocks [0, KC_EDGE): channel-128 path, one (b,r) item per thread.
// Blocks [KC_EDGE, +KC_MAIN): pair-channel main, wave w -> tile blk*4+w;
// lane t runs packed chains {2t,2t+1}; shfl consumed one step late.
// ---------------------------------------------------------------------------
__global__ __launch_bounds__(256, 8) void kC_main(
        const float* __restrict__ wav, const float* __restrict__ B,
        const float* __restrict__ A, const float* __restrict__ zs,
        float* __restrict__ G1, float* __restrict__ G2,
        float* __restrict__ y4f, float beta, float alpha) {
    __shared__ float4 xs4[4 * 48];   // per-wave up to 48-float4 segments
    int blk = blockIdx.x;
    const f2 beta2 = mk2(beta, beta);
    const f2 alpha2 = mk2(alpha, alpha);

    if (blk < KC_EDGE) {
        // ---- edge: channel 128, one (b,r) per thread ----
        int item = blk * 256 + threadIdx.x;
        if (item >= NTC) return;
        int b = item / NHT;
        int r = item - b * NHT;
        int k = r >> 1, half = r & 1;
        C2 q = load_coef2(B, A, 127, 128);
        f2 z0 = mk2(0.f, 0.f), z1 = z0, z2 = z0, z3 = z0, u = z0;
        const float* xg;
        if (r > 0) {
            float4 vx = ((const float4*)zs)[SEQ4(2 * r - 1, b, 127)];
            float4 vy = ((const float4*)zs)[SEQ4(2 * r - 1, b, 128)];
            z0 = mk2(vx.x, vy.x); z1 = mk2(vx.y, vy.y);
            z2 = mk2(vx.z, vy.z); z3 = mk2(vx.w, vy.w);
            xg = wav + (size_t)b * TLEN + (size_t)(2 * r - 1) * CHUNK;
            #pragma unroll 2
            for (int j = 0; j < CHUNK; ++j) WSTEP(xg[j]);
            xg += CHUNK;
        } else {
            xg = wav + (size_t)b * TLEN;
        }
        float g4 = 0.f, yfirst = 0.f;
        #pragma unroll 2
        for (int j = 0; j < TILE; ++j) {
            f2 y_ = iir2_step(q, xg[j], z0, z1, z2, z3);
            u = fma2(beta2, u, sig2(y_));
            float y4 = fmaxf(u.y - u.x, 0.0f);   // ch128 - ch127
            if (j == 0) yfirst = y4;
            g4 = fmaf(alpha, g4, y4);
        }
        size_t idx = ((size_t)b * NFRM + k) * NCH + 128;
        if (half == 0) { G1[idx] = g4; y4f[idx] = yfirst; }
        else           { G2[idx] = g4; }
        return;
    }

    // ---- main: wave w handles tile (blk-KC_EDGE)*4 + w ----
    int wave = threadIdx.x >> 6;
    int t = threadIdx.x & 63;                // lane 0..63
    int tile = (blk - KC_EDGE) * 4 + wave;   // b * NHT + r, < NTC
    int b = tile / NHT;
    int r = tile - b * NHT;
    int k = r >> 1, half = r & 1;
    int n4 = (r > 0) ? 48 : 32;              // (64 warm + 128 main) or 128
    const float* xg = wav + (size_t)b * TLEN +
                      ((r > 0) ? (size_t)(2 * r - 1) * CHUNK : (size_t)0);
    float4* seg = xs4 + wave * 48;
    if (t < n4) seg[t] = ((const float4*)xg)[t];
    __syncthreads();

    int cA = 2 * t, cB = 2 * t + 1;          // chains (cB <= 127)
    C2 q = load_coef2(B, A, cA, cB);
    f2 z0 = mk2(0.f, 0.f), z1 = z0, z2 = z0, z3 = z0, u = z0;
    int gbase = 0;
    if (r > 0) {
        // coalesced: wave reads c = 0..127 consecutive float4s
        float4 vx = ((const float4*)zs)[SEQ4(2 * r - 1, b, cA)];
        float4 vy = ((const float4*)zs)[SEQ4(2 * r - 1, b, cB)];
        z0 = mk2(vx.x, vy.x); z1 = mk2(vx.y, vy.y);
        z2 = mk2(vx.z, vy.z); z3 = mk2(vx.w, vy.w);
        for (int g = 0; g < CHUNK / 4; ++g) {      // 64 warm steps
            float4 xq = seg[g];
            WSTEP(xq.x); WSTEP(xq.y); WSTEP(xq.z); WSTEP(xq.w);
        }
        gbase = CHUNK / 4;
    }

    // main 128 steps; pipeline: ge consumes shfl one step late.
    f2 g2;
    float fo, fe, pend_un, pend_ub;
    {   // first group: peel j=0 and j=1
        float4 xq = seg[gbase];
        // j = 0
        f2 y_ = iir2_step(q, xq.x, z0, z1, z2, z3);
        u = fma2(beta2, u, sig2(y_));
        float un_ = __shfl_down(u.x, 1, 64);
        float y4o_ = fmaxf(u.y - u.x, 0.0f);
        fo = y4o_;
        g2 = mk2(y4o_, 0.0f);
        pend_un = un_; pend_ub = u.y;
        // j = 1
        y_ = iir2_step(q, xq.y, z0, z1, z2, z3);
        u = fma2(beta2, u, sig2(y_));
        un_ = __shfl_down(u.x, 1, 64);
        y4o_ = fmaxf(u.y - u.x, 0.0f);
        float y4e_ = fmaxf(pend_un - pend_ub, 0.0f);
        fe = y4e_;                            // y4e at j=0
        g2 = fma2(alpha2, g2, mk2(y4o_, y4e_));
        pend_un = un_; pend_ub = u.y;
        // j = 2, 3
        MSTEP(xq.z); MSTEP(xq.w);
    }
    for (int g = gbase + 1; g < gbase + TILE / 4; ++g) {
        float4 xq = seg[g];
        MSTEP(xq.x); MSTEP(xq.y); MSTEP(xq.z); MSTEP(xq.w);
    }
    // tail: apply the last pending ge term
    float y4e_last = fmaxf(pend_un - pend_ub, 0.0f);
    float go = g2.x;
    float ge = fmaf(alpha, g2.y, y4e_last);

    size_t base = ((size_t)b * NFRM + k) * NCH;
    if (half == 0) {
        G1[base + cB] = go;            // channel 2t+1 (odd 1..127)
        y4f[base + cB] = fo;
        if (t < 63) {
            G1[base + cB + 1] = ge;    // channel 2t+2 (even 2..126)
            y4f[base + cB + 1] = fe;
        }
    } else {
        G2[base + cB] = go;
        if (t < 63) G2[base + cB + 1] = ge;
    }
}

// ---------------------------------------------------------------------------
// Kernel D: PARALLEL alpha-scan per (b,c) — one wave per sequence.
// Lane l owns frames [4l, 4l+4) (256 >= NFRM=250, padded g=0).
//   o[k] = alpha * s_in[k] + y4f[k];  s' = aL*s + g,  g = aH*G1 + G2.
// Kogge-Stone over lanes with scalar factor (aL^4)^{2^s}.
// ---------------------------------------------------------------------------
#define KD_LOAD(gn, yn, i)                                                     \
    {   int kk = k0 + (i); int kcl = (kk < NFRM) ? kk : (NFRM - 1);            \
        size_t ix = ((size_t)b * NFRM + kcl) * NCH + c;                        \
        gn = fmaf(aH, G1[ix], G2[ix]); yn = y4f[ix];                           \
        if (kk >= NFRM) { gn = 0.f; yn = 0.f; } }
#define KD_REPLAY(gn, yn, i)                                                   \
    {   int kk = k0 + (i);                                                     \
        if (kk < NFRM) o[kk] = fmaf(alpha, sv, yn);                            \
        sv = fmaf(aL, sv, gn); }

__global__ __launch_bounds__(256) void kD_scan_par(
        const float* __restrict__ G1, const float* __restrict__ G2,
        const float* __restrict__ y4f, float* __restrict__ out,
        float alpha, float aL, float aH) {
    int id = blockIdx.x * 4 + (threadIdx.x >> 6);   // b * NCH + c
    int lane = threadIdx.x & 63;
    if (id >= NSEQ) return;
    int b = id / NCH;
    int c = id - b * NCH;
    float* o = out + (size_t)id * NFRM;
    int k0 = lane * 4;
    if (c == 0) {
        #pragma unroll
        for (int i = 0; i < 4; ++i) {
            int kk = k0 + i;
            if (kk < NFRM) o[kk] = 0.0f;
        }
        return;
    }
    float g0, g1, g2v, g3, y0, y1, y2v, y3;
    KD_LOAD(g0, y0, 0); KD_LOAD(g1, y1, 1); KD_LOAD(g2v, y2v, 2); KD_LOAD(g3, y3, 3);
    // local inclusive carry
    float e = g0;
    e = fmaf(aL, e, g1);
    e = fmaf(aL, e, g2v);
    e = fmaf(aL, e, g3);
    // Kogge-Stone with factor f = (aL^4)^{2^s}
    float aL2 = aL * aL;
    float f = aL2 * aL2;                     // aL^4
    for (int s = 0; s < 6; ++s) {
        int off = 1 << s;
        float src = __shfl_up(e, off, 64);
        if (lane < off) src = 0.f;
        e = fmaf(f, src, e);
        f = f * f;
    }
    // exclusive shift
    float sv = __shfl_up(e, 1, 64);
    if (lane == 0) sv = 0.f;
    // replay + store
    KD_REPLAY(g0, y0, 0); KD_REPLAY(g1, y1, 1);
    KD_REPLAY(g2v, y2v, 2); KD_REPLAY(g3, y3, 3);
}

// ---------------------------------------------------------------------------
extern "C" void kernel_launch(void* const* d_in, const int* in_sizes, int n_in,
                              void* d_out, int out_size, void* d_ws, size_t ws_size,
                              hipStream_t stream) {
    const float* wav = (const float*)d_in[0];   // (BS, TLEN)
    const float* Bc  = (const float*)d_in[1];   // (NCH, 5)
    const float* Ac  = (const float*)d_in[2];   // (NCH, 5)
    float* out = (float*)d_out;                 // (BS, NCH, NFRM)

    // workspace: zs (NH*NSEQ float4 = 16.5 MB) | G1 | G2 | y4f (1.03 MB each)
    //            | E (SEG*NSEQ float4 = 660 KB)
    float* zs  = (float*)d_ws;
    float* G1  = zs + (size_t)NH * NSEQ * 4;
    float* G2  = G1 + (size_t)NBK * NCH;
    float* y4f = G2 + (size_t)NBK * NCH;
    float* E   = y4f + (size_t)NBK * NCH;

    const float alpha  = (float)exp(-1.0 / 128.0);
    const float beta   = (float)exp(-1.0 / 8.0);
    const float alphaL = (float)exp(-256.0 / 128.0);   // alpha^256 (frame step)
    const float alphaH = (float)exp(-128.0 / 128.0);   // alpha^128 (half step)

    kA_forced_state<<<KA_EDGE + NT, 128, 0, stream>>>(wav, Bc, Ac, zs);
    kB1_fold<<<SEG * SGRP, 64, 0, stream>>>(Ac, zs, E);
    kB2_carry<<<SGRP, 64, 0, stream>>>(Ac, E);
    kB3_replay<<<SEG * SGRP, 64, 0, stream>>>(Ac, zs, E);
    kC_main<<<KC_EDGE + KC_MAIN, 256, 0, stream>>>(wav, Bc, Ac, zs, G1, G2, y4f, beta, alpha);
    kD_scan_par<<<NSEQ / 4, 256, 0, stream>>>(G1, G2, y4f, out, alpha, alphaL, alphaH);
}

// Round 5
// 140.086 us; speedup vs baseline: 1.2200x; 1.0187x over previous
//
#include <hip/hip_runtime.h>
#include <math.h>

// Problem constants (from reference)
#define NCH 129
#define BS 8
#define TLEN 64000
#define CHUNK 64          // state granularity (zs every 64 samples)
#define NH 1000           // TLEN / CHUNK state chunks
#define TILE 128          // kC tile length (one frame half)
#define NHT 500           // TLEN / TILE tiles per sequence-batch
#define LFRM 256          // frame stride
#define NFRM 250          // number of frames
#define NSEQ (NCH * BS)   // 1032 sequences
#define NBK (BS * NFRM)   // 2000 (b,frame) cells
#define NT (BS * NH)      // 8000 (b,chunk) items (kernel A)
#define NTC (BS * NHT)    // 4000 (b,tile) items (kernel C)
#define KA_EDGE 63        // ceil(NT/128): kA channel-128 blocks
#define KC_EDGE 16        // ceil(NTC/256): kC channel-128 blocks
#define KC_MAIN (NTC / 4) // 1000 main blocks (4 tiles per 256-thr block)
#define SEG 40            // kB segments
#define LSEG 25           // chunks per segment (SEG*LSEG == NH)
#define SGRP 17           // ceil(NSEQ/64) sequence groups per segment

// float4 index of state-chunk h, batch b, channel c.  Layout [h][b][c]:
// c fastest -> kA writes (c = tid) and kC reads (c = 2t,2t+1) are coalesced.
#define SEQ4(h, b, c) ((size_t)(h) * NSEQ + (size_t)(b) * NCH + (c))

typedef float f2 __attribute__((ext_vector_type(2)));

__device__ __forceinline__ f2 mk2(float a, float b) { f2 r; r.x = a; r.y = b; return r; }

__device__ __forceinline__ f2 fma2(f2 a, f2 b, f2 c) {
#if __has_builtin(__builtin_elementwise_fma)
    return __builtin_elementwise_fma(a, b, c);
#else
    f2 r; r.x = fmaf(a.x, b.x, c.x); r.y = fmaf(a.y, b.y, c.y); return r;
#endif
}

__device__ __forceinline__ f2 sig2(f2 v) {
    f2 r;
    r.x = __builtin_amdgcn_rcpf(1.0f + __expf(-v.x));
    r.y = __builtin_amdgcn_rcpf(1.0f + __expf(-v.y));
    return r;
}

// Packed pair-of-chains coefficients.
struct C2 { f2 b0, b1, b2, b3, b4, a1, a2, a3, a4; };

__device__ __forceinline__ C2 load_coef2(const float* __restrict__ B,
                                         const float* __restrict__ A,
                                         int cx, int cy) {
    C2 q;
    q.b0 = mk2(B[cx * 5 + 0], B[cy * 5 + 0]);
    q.b1 = mk2(B[cx * 5 + 1], B[cy * 5 + 1]);
    q.b2 = mk2(B[cx * 5 + 2], B[cy * 5 + 2]);
    q.b3 = mk2(B[cx * 5 + 3], B[cy * 5 + 3]);
    q.b4 = mk2(B[cx * 5 + 4], B[cy * 5 + 4]);
    q.a1 = mk2(A[cx * 5 + 1], A[cy * 5 + 1]);
    q.a2 = mk2(A[cx * 5 + 2], A[cy * 5 + 2]);
    q.a3 = mk2(A[cx * 5 + 3], A[cy * 5 + 3]);
    q.a4 = mk2(A[cx * 5 + 4], A[cy * 5 + 4]);
    return q;
}

__device__ __forceinline__ f2 iir2_step(const C2& q, float x,
                                        f2& z0, f2& z1, f2& z2, f2& z3) {
    f2 xx = mk2(x, x);
    f2 y = fma2(q.b0, xx, z0);
    z0 = fma2(-q.a1, y, fma2(q.b1, xx, z1));
    z1 = fma2(-q.a2, y, fma2(q.b2, xx, z2));
    z2 = fma2(-q.a3, y, fma2(q.b3, xx, z3));
    z3 = fma2(-q.a4, y, q.b4 * xx);
    return y;
}

// Scalar variants (kernel A only).
struct Coef { float b0, b1, b2, b3, b4, a1, a2, a3, a4; };
__device__ __forceinline__ Coef load_coef(const float* __restrict__ B,
                                          const float* __restrict__ A, int c) {
    Coef q;
    q.b0 = B[c * 5 + 0]; q.b1 = B[c * 5 + 1]; q.b2 = B[c * 5 + 2];
    q.b3 = B[c * 5 + 3]; q.b4 = B[c * 5 + 4];
    q.a1 = A[c * 5 + 1]; q.a2 = A[c * 5 + 2];
    q.a3 = A[c * 5 + 3]; q.a4 = A[c * 5 + 4];
    return q;
}
__device__ __forceinline__ float iir_step(const Coef& q, float x,
                                          float& z0, float& z1, float& z2, float& z3) {
    float y = fmaf(q.b0, x, z0);
    z0 = fmaf(-q.a1, y, fmaf(q.b1, x, z1));
    z1 = fmaf(-q.a2, y, fmaf(q.b2, x, z2));
    z2 = fmaf(-q.a3, y, fmaf(q.b3, x, z3));
    z3 = fmaf(-q.a4, y, q.b4 * x);
    return y;
}

// step macros for packed chains (coef struct must be named q)
#define WSTEP(xv)                                                              \
    { f2 y_ = iir2_step(q, (xv), z0, z1, z2, z3);                              \
      u = fma2(beta2, u, sig2(y_)); }
#define MSTEP(xv)                                                              \
    { f2 y_ = iir2_step(q, (xv), z0, z1, z2, z3);                              \
      u = fma2(beta2, u, sig2(y_));                                            \
      float un_ = __shfl_down(u.x, 1, 64);                                     \
      float y4o_ = fmaxf(u.y - u.x, 0.0f);                                     \
      float y4e_ = fmaxf(pend_un - pend_ub, 0.0f);                             \
      g2 = fma2(alpha2, g2, mk2(y4o_, y4e_));                                  \
      pend_un = un_; pend_ub = u.y; }

// ---- 4x4 matrix helpers over 16 NAMED scalars (no arrays -> no scratch) ----
#define MDECL(X) float X##00, X##01, X##02, X##03, X##10, X##11, X##12, X##13, \
                       X##20, X##21, X##22, X##23, X##30, X##31, X##32, X##33
#define MCOPY(D, S) D##00=S##00; D##01=S##01; D##02=S##02; D##03=S##03;        \
                    D##10=S##10; D##11=S##11; D##12=S##12; D##13=S##13;        \
                    D##20=S##20; D##21=S##21; D##22=S##22; D##23=S##23;        \
                    D##30=S##30; D##31=S##31; D##32=S##32; D##33=S##33
#define MROW(R, X, Y, i)                                                       \
    R##i##0 = fmaf(X##i##0, Y##00, fmaf(X##i##1, Y##10, fmaf(X##i##2, Y##20, X##i##3 * Y##30))); \
    R##i##1 = fmaf(X##i##0, Y##01, fmaf(X##i##1, Y##11, fmaf(X##i##2, Y##21, X##i##3 * Y##31))); \
    R##i##2 = fmaf(X##i##0, Y##02, fmaf(X##i##1, Y##12, fmaf(X##i##2, Y##22, X##i##3 * Y##32))); \
    R##i##3 = fmaf(X##i##0, Y##03, fmaf(X##i##1, Y##13, fmaf(X##i##2, Y##23, X##i##3 * Y##33)))
#define MMUL(R, X, Y) MROW(R, X, Y, 0); MROW(R, X, Y, 1); MROW(R, X, Y, 2); MROW(R, X, Y, 3)
// r (float4) = X * v (float4)
#define MV(r, X, v)                                                            \
    r.x = fmaf(X##00, v.x, fmaf(X##01, v.y, fmaf(X##02, v.z, X##03 * v.w)));   \
    r.y = fmaf(X##10, v.x, fmaf(X##11, v.y, fmaf(X##12, v.z, X##13 * v.w)));   \
    r.z = fmaf(X##20, v.x, fmaf(X##21, v.y, fmaf(X##22, v.z, X##23 * v.w)));   \
    r.w = fmaf(X##30, v.x, fmaf(X##31, v.y, fmaf(X##32, v.z, X##33 * v.w)))
// build companion matrix M and raise to M^64 (6 squarings)
#define BUILD_M64(M1, a1, a2, a3, a4)                                          \
    M1##00 = -(a1); M1##01 = 1.f; M1##02 = 0.f; M1##03 = 0.f;                  \
    M1##10 = -(a2); M1##11 = 0.f; M1##12 = 1.f; M1##13 = 0.f;                  \
    M1##20 = -(a3); M1##21 = 0.f; M1##22 = 0.f; M1##23 = 1.f;                  \
    M1##30 = -(a4); M1##31 = 0.f; M1##32 = 0.f; M1##33 = 0.f;                  \
    for (int s_ = 0; s_ < 6; ++s_) { MDECL(T_); MMUL(T_, M1, M1); MCOPY(M1, T_); }

// affine step helper: e = M*e + d
#define AFF_STEP(M, e, d)                                                      \
    {   float4 t_; MV(t_, M, e);                                               \
        e.x = t_.x + d.x; e.y = t_.y + d.y;                                    \
        e.z = t_.z + d.z; e.w = t_.w + d.w; }

// ---------------------------------------------------------------------------
// Kernel A: forced-response state per (c, b, 64-chunk h), zero initial state.
// Blocks [0, KA_EDGE): channel 128 — one (b,h) item per thread (128/block).
// Blocks [KA_EDGE, +NT): channels 0..127 — 128 threads, LDS-staged x.
// zs[h][b][c] float4 = forced response d[h] (chunk from zero state).
// ---------------------------------------------------------------------------
__global__ __launch_bounds__(128, 8) void kA_forced_state(
        const float* __restrict__ wav, const float* __restrict__ B,
        const float* __restrict__ A, float* __restrict__ zs) {
    __shared__ float xs[CHUNK];
    int blk = blockIdx.x;
    if (blk < KA_EDGE) {
        int item = blk * 128 + threadIdx.x;
        if (item >= NT) return;
        int b = item / NH;
        int h = item - b * NH;
        const float* xg = wav + (size_t)b * TLEN + (size_t)h * CHUNK;
        Coef q = load_coef(B, A, 128);
        float z0 = 0.f, z1 = 0.f, z2 = 0.f, z3 = 0.f;
        #pragma unroll 4
        for (int j = 0; j < CHUNK; ++j) {
            (void)iir_step(q, xg[j], z0, z1, z2, z3);
        }
        ((float4*)zs)[SEQ4(h, b, 128)] = make_float4(z0, z1, z2, z3);
        return;
    }
    int mblk = blk - KA_EDGE;        // b * NH + h
    int b = mblk / NH;
    int h = mblk - b * NH;
    const float* xg = wav + (size_t)b * TLEN + (size_t)h * CHUNK;
    if (threadIdx.x < CHUNK) xs[threadIdx.x] = xg[threadIdx.x];
    __syncthreads();
    int c = threadIdx.x;             // 0..127
    Coef q = load_coef(B, A, c);
    float z0 = 0.f, z1 = 0.f, z2 = 0.f, z3 = 0.f;
    #pragma unroll 8
    for (int j = 0; j < CHUNK; ++j) {
        (void)iir_step(q, xs[j], z0, z1, z2, z3);
    }
    ((float4*)zs)[SEQ4(h, b, c)] = make_float4(z0, z1, z2, z3);  // coalesced in c
}

// ---------------------------------------------------------------------------
// Kernel B (3-pass segmented affine scan, lane-coalesced).
// Sequence id s = b*NCH + c in [0,NSEQ); lanes span consecutive s so every
// zs access is a contiguous 1 KB wave transaction.
// kB1: per (seg, s): E[seg][s] = forced response of segment (fold 25 d's).
// kB2: per s: serial scan over 40 segment carries with ML = M64^25;
//      overwrites E[seg][s] with the EXCLUSIVE segment-start state.
// kB3: per (seg, s): replay 25 chunks from start state, writing exact
//      state into zs[h] for ODD h only (the only states kC reads).
// ---------------------------------------------------------------------------
__global__ __launch_bounds__(64) void kB1_fold(
        const float* __restrict__ A, const float* __restrict__ zs,
        float* __restrict__ E) {
    int seg = blockIdx.x / SGRP;
    int s = (blockIdx.x % SGRP) * 64 + threadIdx.x;
    if (s >= NSEQ) return;
    int c = s % NCH;
    float a1 = A[c * 5 + 1], a2 = A[c * 5 + 2], a3 = A[c * 5 + 3], a4 = A[c * 5 + 4];
    MDECL(M1); BUILD_M64(M1, a1, a2, a3, a4);
    const float4* zb = (const float4*)zs;
    float4 e = make_float4(0.f, 0.f, 0.f, 0.f);
    size_t base = (size_t)seg * LSEG * NSEQ + s;
    #pragma unroll 5
    for (int i = 0; i < LSEG; ++i) {
        float4 d = zb[base + (size_t)i * NSEQ];
        AFF_STEP(M1, e, d);
    }
    ((float4*)E)[(size_t)seg * NSEQ + s] = e;
}

__global__ __launch_bounds__(64) void kB2_carry(
        const float* __restrict__ A, float* __restrict__ E) {
    int s = blockIdx.x * 64 + threadIdx.x;
    if (s >= NSEQ) return;
    int c = s % NCH;
    float a1 = A[c * 5 + 1], a2 = A[c * 5 + 2], a3 = A[c * 5 + 3], a4 = A[c * 5 + 4];
    MDECL(M1); BUILD_M64(M1, a1, a2, a3, a4);
    // ML = M1^25 = M1^16 * M1^8 * M1
    MDECL(P8);
    { MDECL(T); MMUL(T, M1, M1); MDECL(P4); MMUL(P4, T, T); MMUL(P8, P4, P4); }
    MDECL(ML);
    { MDECL(P16); MMUL(P16, P8, P8); MDECL(P24); MMUL(P24, P16, P8);
      MMUL(ML, P24, M1); }
    float4* E4 = (float4*)E;
    float4 Z = make_float4(0.f, 0.f, 0.f, 0.f);
    for (int seg = 0; seg < SEG; ++seg) {
        size_t ix = (size_t)seg * NSEQ + s;
        float4 Eseg = E4[ix];
        E4[ix] = Z;                  // exclusive segment-start state
        AFF_STEP(ML, Z, Eseg);
    }
}

__global__ __launch_bounds__(64) void kB3_replay(
        const float* __restrict__ A, float* __restrict__ zs,
        const float* __restrict__ E) {
    int seg = blockIdx.x / SGRP;
    int s = (blockIdx.x % SGRP) * 64 + threadIdx.x;
    if (s >= NSEQ) return;
    int c = s % NCH;
    float a1 = A[c * 5 + 1], a2 = A[c * 5 + 2], a3 = A[c * 5 + 3], a4 = A[c * 5 + 4];
    MDECL(M1); BUILD_M64(M1, a1, a2, a3, a4);
    float4* zb = (float4*)zs;
    float4 z = ((const float4*)E)[(size_t)seg * NSEQ + s];
    int h0 = seg * LSEG;
    #pragma unroll 5
    for (int i = 0; i < LSEG; ++i) {
        size_t ix = (size_t)(h0 + i) * NSEQ + s;
        float4 d = zb[ix];           // read forced response BEFORE overwrite
        if ((h0 + i) & 1) zb[ix] = z;  // exact state; only odd h consumed
        AFF_STEP(M1, z, d);
    }
}

// ---------------------------------------------------------------------------
// Kernel C: 128-sample frame-half tiles, 256-thr blocks (4 tiles/block).
// Tile r in [0, NHT) covers samples [128r, 128r+128); frame k = r>>1,
// half = r&1. Warm-up: 64 WSTEPs over [128r-64, 128r) from the EXACT
// state zs[2r-1] (beta^64 = 3.4e-4 u-truncation, z exact).
// R5 = R4 pipelining with the warm-loop bound FIXED (CHUNK/4 groups, not
// CHUNK/16): prefetch seg[g+1] before consuming seg[g]; math identical to R3.
// Blocks [0, KC_EDGE): channel-128 path, one (b,r) item per thread.
// Blocks [KC_EDGE, +KC_MAIN): pair-channel main, wave w -> tile blk*4+w;
// lane t runs packed chains {2t,2t+1}; shfl consumed one step late.
// ---------------------------------------------------------------------------
__global__ __launch_bounds__(256, 8) void kC_main(
        const float* __restrict__ wav, const float* __restrict__ B,
        const float* __restrict__ A, const float* __restrict__ zs,
        float* __restrict__ G1, float* __restrict__ G2,
        float* __restrict__ y4f, float beta, float alpha) {
    __shared__ float4 xs4[4 * 48];   // per-wave up to 48-float4 segments
    int blk = blockIdx.x;
    const f2 beta2 = mk2(beta, beta);
    const f2 alpha2 = mk2(alpha, alpha);

    if (blk < KC_EDGE) {
        // ---- edge: channel 128, one (b,r) per thread ----
        int item = blk * 256 + threadIdx.x;
        if (item >= NTC) return;
        int b = item / NHT;
        int r = item - b * NHT;
        int k = r >> 1, half = r & 1;
        C2 q = load_coef2(B, A, 127, 128);
        f2 z0 = mk2(0.f, 0.f), z1 = z0, z2 = z0, z3 = z0, u = z0;
        const float* xg;
        if (r > 0) {
            float4 vx = ((const float4*)zs)[SEQ4(2 * r - 1, b, 127)];
            float4 vy = ((const float4*)zs)[SEQ4(2 * r - 1, b, 128)];
            z0 = mk2(vx.x, vy.x); z1 = mk2(vx.y, vy.y);
            z2 = mk2(vx.z, vy.z); z3 = mk2(vx.w, vy.w);
            xg = wav + (size_t)b * TLEN + (size_t)(2 * r - 1) * CHUNK;
            #pragma unroll 2
            for (int j = 0; j < CHUNK; ++j) WSTEP(xg[j]);
            xg += CHUNK;
        } else {
            xg = wav + (size_t)b * TLEN;
        }
        float g4 = 0.f, yfirst = 0.f;
        #pragma unroll 2
        for (int j = 0; j < TILE; ++j) {
            f2 y_ = iir2_step(q, xg[j], z0, z1, z2, z3);
            u = fma2(beta2, u, sig2(y_));
            float y4 = fmaxf(u.y - u.x, 0.0f);   // ch128 - ch127
            if (j == 0) yfirst = y4;
            g4 = fmaf(alpha, g4, y4);
        }
        size_t idx = ((size_t)b * NFRM + k) * NCH + 128;
        if (half == 0) { G1[idx] = g4; y4f[idx] = yfirst; }
        else           { G2[idx] = g4; }
        return;
    }

    // ---- main: wave w handles tile (blk-KC_EDGE)*4 + w ----
    int wave = threadIdx.x >> 6;
    int t = threadIdx.x & 63;                // lane 0..63
    int tile = (blk - KC_EDGE) * 4 + wave;   // b * NHT + r, < NTC
    int b = tile / NHT;
    int r = tile - b * NHT;
    int k = r >> 1, half = r & 1;
    int n4 = (r > 0) ? 48 : 32;              // (64 warm + 128 main) or 128
    int gend = n4;
    const float* xg = wav + (size_t)b * TLEN +
                      ((r > 0) ? (size_t)(2 * r - 1) * CHUNK : (size_t)0);
    float4* seg = xs4 + wave * 48;
    if (t < n4) seg[t] = ((const float4*)xg)[t];
    __syncthreads();

    int cA = 2 * t, cB = 2 * t + 1;          // chains (cB <= 127)
    C2 q = load_coef2(B, A, cA, cB);
    f2 z0 = mk2(0.f, 0.f), z1 = z0, z2 = z0, z3 = z0, u = z0;
    int gbase = 0;
    float4 xq = seg[0];                      // pipeline head
    if (r > 0) {
        // coalesced: wave reads c = 0..127 consecutive float4s
        float4 vx = ((const float4*)zs)[SEQ4(2 * r - 1, b, cA)];
        float4 vy = ((const float4*)zs)[SEQ4(2 * r - 1, b, cB)];
        z0 = mk2(vx.x, vy.x); z1 = mk2(vx.y, vy.y);
        z2 = mk2(vx.z, vy.z); z3 = mk2(vx.w, vy.w);
        for (int g = 0; g < CHUNK / 4; ++g) {      // 16 groups = 64 warm steps
            float4 xn = seg[g + 1];                // prefetch (g+1 <= 16 < 48)
            WSTEP(xq.x); WSTEP(xq.y); WSTEP(xq.z); WSTEP(xq.w);
            xq = xn;
        }
        gbase = CHUNK / 4;                         // xq == seg[16]
    }

    // main 128 steps; pipeline: ge consumes shfl one step late.
    f2 g2;
    float fo, fe, pend_un, pend_ub;
    {   // first group: peel j=0 and j=1   (xq == seg[gbase])
        float4 xn = seg[gbase + 1];                // prefetch next group
        // j = 0
        f2 y_ = iir2_step(q, xq.x, z0, z1, z2, z3);
        u = fma2(beta2, u, sig2(y_));
        float un_ = __shfl_down(u.x, 1, 64);
        float y4o_ = fmaxf(u.y - u.x, 0.0f);
        fo = y4o_;
        g2 = mk2(y4o_, 0.0f);
        pend_un = un_; pend_ub = u.y;
        // j = 1
        y_ = iir2_step(q, xq.y, z0, z1, z2, z3);
        u = fma2(beta2, u, sig2(y_));
        un_ = __shfl_down(u.x, 1, 64);
        y4o_ = fmaxf(u.y - u.x, 0.0f);
        float y4e_ = fmaxf(pend_un - pend_ub, 0.0f);
        fe = y4e_;                            // y4e at j=0
        g2 = fma2(alpha2, g2, mk2(y4o_, y4e_));
        pend_un = un_; pend_ub = u.y;
        // j = 2, 3
        MSTEP(xq.z); MSTEP(xq.w);
        xq = xn;
    }
    for (int g = gbase + 1; g < gbase + TILE / 4; ++g) {
        int gn = g + 1; if (gn >= gend) gn = g;    // uniform clamp (stay in seg)
        float4 xn = seg[gn];                       // prefetch next group
        MSTEP(xq.x); MSTEP(xq.y); MSTEP(xq.z); MSTEP(xq.w);
        xq = xn;
    }
    // tail: apply the last pending ge term
    float y4e_last = fmaxf(pend_un - pend_ub, 0.0f);
    float go = g2.x;
    float ge = fmaf(alpha, g2.y, y4e_last);

    size_t base = ((size_t)b * NFRM + k) * NCH;
    if (half == 0) {
        G1[base + cB] = go;            // channel 2t+1 (odd 1..127)
        y4f[base + cB] = fo;
        if (t < 63) {
            G1[base + cB + 1] = ge;    // channel 2t+2 (even 2..126)
            y4f[base + cB + 1] = fe;
        }
    } else {
        G2[base + cB] = go;
        if (t < 63) G2[base + cB + 1] = ge;
    }
}

// ---------------------------------------------------------------------------
// Kernel D: PARALLEL alpha-scan per (b,c) — one wave per sequence.
// Lane l owns frames [4l, 4l+4) (256 >= NFRM=250, padded g=0).
//   o[k] = alpha * s_in[k] + y4f[k];  s' = aL*s + g,  g = aH*G1 + G2.
// Kogge-Stone over lanes with scalar factor (aL^4)^{2^s}.
// ---------------------------------------------------------------------------
#define KD_LOAD(gn, yn, i)                                                     \
    {   int kk = k0 + (i); int kcl = (kk < NFRM) ? kk : (NFRM - 1);            \
        size_t ix = ((size_t)b * NFRM + kcl) * NCH + c;                        \
        gn = fmaf(aH, G1[ix], G2[ix]); yn = y4f[ix];                           \
        if (kk >= NFRM) { gn = 0.f; yn = 0.f; } }
#define KD_REPLAY(gn, yn, i)                                                   \
    {   int kk = k0 + (i);                                                     \
        if (kk < NFRM) o[kk] = fmaf(alpha, sv, yn);                            \
        sv = fmaf(aL, sv, gn); }

__global__ __launch_bounds__(256) void kD_scan_par(
        const float* __restrict__ G1, const float* __restrict__ G2,
        const float* __restrict__ y4f, float* __restrict__ out,
        float alpha, float aL, float aH) {
    int id = blockIdx.x * 4 + (threadIdx.x >> 6);   // b * NCH + c
    int lane = threadIdx.x & 63;
    if (id >= NSEQ) return;
    int b = id / NCH;
    int c = id - b * NCH;
    float* o = out + (size_t)id * NFRM;
    int k0 = lane * 4;
    if (c == 0) {
        #pragma unroll
        for (int i = 0; i < 4; ++i) {
            int kk = k0 + i;
            if (kk < NFRM) o[kk] = 0.0f;
        }
        return;
    }
    float g0, g1, g2v, g3, y0, y1, y2v, y3;
    KD_LOAD(g0, y0, 0); KD_LOAD(g1, y1, 1); KD_LOAD(g2v, y2v, 2); KD_LOAD(g3, y3, 3);
    // local inclusive carry
    float e = g0;
    e = fmaf(aL, e, g1);
    e = fmaf(aL, e, g2v);
    e = fmaf(aL, e, g3);
    // Kogge-Stone with factor f = (aL^4)^{2^s}
    float aL2 = aL * aL;
    float f = aL2 * aL2;                     // aL^4
    for (int s = 0; s < 6; ++s) {
        int off = 1 << s;
        float src = __shfl_up(e, off, 64);
        if (lane < off) src = 0.f;
        e = fmaf(f, src, e);
        f = f * f;
    }
    // exclusive shift
    float sv = __shfl_up(e, 1, 64);
    if (lane == 0) sv = 0.f;
    // replay + store
    KD_REPLAY(g0, y0, 0); KD_REPLAY(g1, y1, 1);
    KD_REPLAY(g2v, y2v, 2); KD_REPLAY(g3, y3, 3);
}

// ---------------------------------------------------------------------------
extern "C" void kernel_launch(void* const* d_in, const int* in_sizes, int n_in,
                              void* d_out, int out_size, void* d_ws, size_t ws_size,
                              hipStream_t stream) {
    const float* wav = (const float*)d_in[0];   // (BS, TLEN)
    const float* Bc  = (const float*)d_in[1];   // (NCH, 5)
    const float* Ac  = (const float*)d_in[2];   // (NCH, 5)
    float* out = (float*)d_out;                 // (BS, NCH, NFRM)

    // workspace: zs (NH*NSEQ float4 = 16.5 MB) | G1 | G2 | y4f (1.03 MB each)
    //            | E (SEG*NSEQ float4 = 660 KB)
    float* zs  = (float*)d_ws;
    float* G1  = zs + (size_t)NH * NSEQ * 4;
    float* G2  = G1 + (size_t)NBK * NCH;
    float* y4f = G2 + (size_t)NBK * NCH;
    float* E   = y4f + (size_t)NBK * NCH;

    const float alpha  = (float)exp(-1.0 / 128.0);
    const float beta   = (float)exp(-1.0 / 8.0);
    const float alphaL = (float)exp(-256.0 / 128.0);   // alpha^256 (frame step)
    const float alphaH = (float)exp(-128.0 / 128.0);   // alpha^128 (half step)

    kA_forced_state<<<KA_EDGE + NT, 128, 0, stream>>>(wav, Bc, Ac, zs);
    kB1_fold<<<SEG * SGRP, 64, 0, stream>>>(Ac, zs, E);
    kB2_carry<<<SGRP, 64, 0, stream>>>(Ac, E);
    kB3_replay<<<SEG * SGRP, 64, 0, stream>>>(Ac, zs, E);
    kC_main<<<KC_EDGE + KC_MAIN, 256, 0, stream>>>(wav, Bc, Ac, zs, G1, G2, y4f, beta, alpha);
    kD_scan_par<<<NSEQ / 4, 256, 0, stream>>>(G1, G2, y4f, out, alpha, alphaL, alphaH);
}

// Round 6
// 138.533 us; speedup vs baseline: 1.2337x; 1.0112x over previous
//
#include <hip/hip_runtime.h>
#include <math.h>

// Problem constants (from reference)
#define NCH 129
#define BS 8
#define TLEN 64000
#define CHUNK 64          // state granularity (zs every 64 samples)
#define NH 1000           // TLEN / CHUNK state chunks
#define TILE 256          // kC tile length (one FULL frame)
#define LFRM 256          // frame stride
#define NFRM 250          // number of frames
#define NSEQ (NCH * BS)   // 1032 sequences
#define NBK (BS * NFRM)   // 2000 (b,frame) cells
#define NT (BS * NH)      // 8000 (b,chunk) items (kernel A)
#define KA_EDGE 63        // ceil(NT/128): kA channel-128 blocks
#define KC_EDGE 8         // ceil(NBK/256): kC channel-128 blocks
#define KC_MAIN (NBK / 4) // 500 main blocks (4 frame-tiles per 256-thr block)
#define SEG 40            // kB segments
#define LSEG 25           // chunks per segment (SEG*LSEG == NH)
#define SGRP 17           // ceil(NSEQ/64) sequence groups per segment

// float4 index of state-chunk h, batch b, channel c.  Layout [h][b][c]:
// c fastest -> kA writes (c = tid) and kC reads (c = 2t,2t+1) are coalesced.
#define SEQ4(h, b, c) ((size_t)(h) * NSEQ + (size_t)(b) * NCH + (c))

typedef float f2 __attribute__((ext_vector_type(2)));

__device__ __forceinline__ f2 mk2(float a, float b) { f2 r; r.x = a; r.y = b; return r; }

__device__ __forceinline__ f2 fma2(f2 a, f2 b, f2 c) {
#if __has_builtin(__builtin_elementwise_fma)
    return __builtin_elementwise_fma(a, b, c);
#else
    f2 r; r.x = fmaf(a.x, b.x, c.x); r.y = fmaf(a.y, b.y, c.y); return r;
#endif
}

__device__ __forceinline__ f2 sig2(f2 v) {
    f2 r;
    r.x = __builtin_amdgcn_rcpf(1.0f + __expf(-v.x));
    r.y = __builtin_amdgcn_rcpf(1.0f + __expf(-v.y));
    return r;
}

// Packed pair-of-chains coefficients.
struct C2 { f2 b0, b1, b2, b3, b4, a1, a2, a3, a4; };

__device__ __forceinline__ C2 load_coef2(const float* __restrict__ B,
                                         const float* __restrict__ A,
                                         int cx, int cy) {
    C2 q;
    q.b0 = mk2(B[cx * 5 + 0], B[cy * 5 + 0]);
    q.b1 = mk2(B[cx * 5 + 1], B[cy * 5 + 1]);
    q.b2 = mk2(B[cx * 5 + 2], B[cy * 5 + 2]);
    q.b3 = mk2(B[cx * 5 + 3], B[cy * 5 + 3]);
    q.b4 = mk2(B[cx * 5 + 4], B[cy * 5 + 4]);
    q.a1 = mk2(A[cx * 5 + 1], A[cy * 5 + 1]);
    q.a2 = mk2(A[cx * 5 + 2], A[cy * 5 + 2]);
    q.a3 = mk2(A[cx * 5 + 3], A[cy * 5 + 3]);
    q.a4 = mk2(A[cx * 5 + 4], A[cy * 5 + 4]);
    return q;
}

__device__ __forceinline__ f2 iir2_step(const C2& q, float x,
                                        f2& z0, f2& z1, f2& z2, f2& z3) {
    f2 xx = mk2(x, x);
    f2 y = fma2(q.b0, xx, z0);
    z0 = fma2(-q.a1, y, fma2(q.b1, xx, z1));
    z1 = fma2(-q.a2, y, fma2(q.b2, xx, z2));
    z2 = fma2(-q.a3, y, fma2(q.b3, xx, z3));
    z3 = fma2(-q.a4, y, q.b4 * xx);
    return y;
}

// Scalar variants (kernel A only).
struct Coef { float b0, b1, b2, b3, b4, a1, a2, a3, a4; };
__device__ __forceinline__ Coef load_coef(const float* __restrict__ B,
                                          const float* __restrict__ A, int c) {
    Coef q;
    q.b0 = B[c * 5 + 0]; q.b1 = B[c * 5 + 1]; q.b2 = B[c * 5 + 2];
    q.b3 = B[c * 5 + 3]; q.b4 = B[c * 5 + 4];
    q.a1 = A[c * 5 + 1]; q.a2 = A[c * 5 + 2];
    q.a3 = A[c * 5 + 3]; q.a4 = A[c * 5 + 4];
    return q;
}
__device__ __forceinline__ float iir_step(const Coef& q, float x,
                                          float& z0, float& z1, float& z2, float& z3) {
    float y = fmaf(q.b0, x, z0);
    z0 = fmaf(-q.a1, y, fmaf(q.b1, x, z1));
    z1 = fmaf(-q.a2, y, fmaf(q.b2, x, z2));
    z2 = fmaf(-q.a3, y, fmaf(q.b3, x, z3));
    z3 = fmaf(-q.a4, y, q.b4 * x);
    return y;
}

// step macros for packed chains (coef struct must be named q)
#define WSTEP(xv)                                                              \
    { f2 y_ = iir2_step(q, (xv), z0, z1, z2, z3);                              \
      u = fma2(beta2, u, sig2(y_)); }
#define MSTEP(xv)                                                              \
    { f2 y_ = iir2_step(q, (xv), z0, z1, z2, z3);                              \
      u = fma2(beta2, u, sig2(y_));                                            \
      float un_ = __shfl_down(u.x, 1, 64);                                     \
      float y4o_ = fmaxf(u.y - u.x, 0.0f);                                     \
      float y4e_ = fmaxf(pend_un - pend_ub, 0.0f);                             \
      g2 = fma2(alpha2, g2, mk2(y4o_, y4e_));                                  \
      pend_un = un_; pend_ub = u.y; }

// ---- 4x4 matrix helpers over 16 NAMED scalars (no arrays -> no scratch) ----
#define MDECL(X) float X##00, X##01, X##02, X##03, X##10, X##11, X##12, X##13, \
                       X##20, X##21, X##22, X##23, X##30, X##31, X##32, X##33
#define MCOPY(D, S) D##00=S##00; D##01=S##01; D##02=S##02; D##03=S##03;        \
                    D##10=S##10; D##11=S##11; D##12=S##12; D##13=S##13;        \
                    D##20=S##20; D##21=S##21; D##22=S##22; D##23=S##23;        \
                    D##30=S##30; D##31=S##31; D##32=S##32; D##33=S##33
#define MROW(R, X, Y, i)                                                       \
    R##i##0 = fmaf(X##i##0, Y##00, fmaf(X##i##1, Y##10, fmaf(X##i##2, Y##20, X##i##3 * Y##30))); \
    R##i##1 = fmaf(X##i##0, Y##01, fmaf(X##i##1, Y##11, fmaf(X##i##2, Y##21, X##i##3 * Y##31))); \
    R##i##2 = fmaf(X##i##0, Y##02, fmaf(X##i##1, Y##12, fmaf(X##i##2, Y##22, X##i##3 * Y##32))); \
    R##i##3 = fmaf(X##i##0, Y##03, fmaf(X##i##1, Y##13, fmaf(X##i##2, Y##23, X##i##3 * Y##33)))
#define MMUL(R, X, Y) MROW(R, X, Y, 0); MROW(R, X, Y, 1); MROW(R, X, Y, 2); MROW(R, X, Y, 3)
// r (float4) = X * v (float4)
#define MV(r, X, v)                                                            \
    r.x = fmaf(X##00, v.x, fmaf(X##01, v.y, fmaf(X##02, v.z, X##03 * v.w)));   \
    r.y = fmaf(X##10, v.x, fmaf(X##11, v.y, fmaf(X##12, v.z, X##13 * v.w)));   \
    r.z = fmaf(X##20, v.x, fmaf(X##21, v.y, fmaf(X##22, v.z, X##23 * v.w)));   \
    r.w = fmaf(X##30, v.x, fmaf(X##31, v.y, fmaf(X##32, v.z, X##33 * v.w)))
// build companion matrix M and raise to M^64 (6 squarings)
#define BUILD_M64(M1, a1, a2, a3, a4)                                          \
    M1##00 = -(a1); M1##01 = 1.f; M1##02 = 0.f; M1##03 = 0.f;                  \
    M1##10 = -(a2); M1##11 = 0.f; M1##12 = 1.f; M1##13 = 0.f;                  \
    M1##20 = -(a3); M1##21 = 0.f; M1##22 = 0.f; M1##23 = 1.f;                  \
    M1##30 = -(a4); M1##31 = 0.f; M1##32 = 0.f; M1##33 = 0.f;                  \
    for (int s_ = 0; s_ < 6; ++s_) { MDECL(T_); MMUL(T_, M1, M1); MCOPY(M1, T_); }

// affine step helper: e = M*e + d
#define AFF_STEP(M, e, d)                                                      \
    {   float4 t_; MV(t_, M, e);                                               \
        e.x = t_.x + d.x; e.y = t_.y + d.y;                                    \
        e.z = t_.z + d.z; e.w = t_.w + d.w; }

// ---------------------------------------------------------------------------
// Kernel A: forced-response state per (c, b, 64-chunk h), zero initial state.
// Blocks [0, KA_EDGE): channel 128 — one (b,h) item per thread (128/block).
// Blocks [KA_EDGE, +NT): channels 0..127 — 128 threads, LDS-staged x.
// zs[h][b][c] float4 = forced response d[h] (chunk from zero state).
// ---------------------------------------------------------------------------
__global__ __launch_bounds__(128, 8) void kA_forced_state(
        const float* __restrict__ wav, const float* __restrict__ B,
        const float* __restrict__ A, float* __restrict__ zs) {
    __shared__ float xs[CHUNK];
    int blk = blockIdx.x;
    if (blk < KA_EDGE) {
        int item = blk * 128 + threadIdx.x;
        if (item >= NT) return;
        int b = item / NH;
        int h = item - b * NH;
        const float* xg = wav + (size_t)b * TLEN + (size_t)h * CHUNK;
        Coef q = load_coef(B, A, 128);
        float z0 = 0.f, z1 = 0.f, z2 = 0.f, z3 = 0.f;
        #pragma unroll 4
        for (int j = 0; j < CHUNK; ++j) {
            (void)iir_step(q, xg[j], z0, z1, z2, z3);
        }
        ((float4*)zs)[SEQ4(h, b, 128)] = make_float4(z0, z1, z2, z3);
        return;
    }
    int mblk = blk - KA_EDGE;        // b * NH + h
    int b = mblk / NH;
    int h = mblk - b * NH;
    const float* xg = wav + (size_t)b * TLEN + (size_t)h * CHUNK;
    if (threadIdx.x < CHUNK) xs[threadIdx.x] = xg[threadIdx.x];
    __syncthreads();
    int c = threadIdx.x;             // 0..127
    Coef q = load_coef(B, A, c);
    float z0 = 0.f, z1 = 0.f, z2 = 0.f, z3 = 0.f;
    #pragma unroll 8
    for (int j = 0; j < CHUNK; ++j) {
        (void)iir_step(q, xs[j], z0, z1, z2, z3);
    }
    ((float4*)zs)[SEQ4(h, b, c)] = make_float4(z0, z1, z2, z3);  // coalesced in c
}

// ---------------------------------------------------------------------------
// Kernel B (3-pass segmented affine scan, lane-coalesced).
// Sequence id s = b*NCH + c in [0,NSEQ); lanes span consecutive s so every
// zs access is a contiguous 1 KB wave transaction.
// kB1: per (seg, s): E[seg][s] = forced response of segment (fold 25 d's).
// kB2: per s: serial scan over 40 segment carries with ML = M64^25;
//      software-pipelined (load seg+1 before the dependent AFF_STEP on seg).
// kB3: per (seg, s): replay 25 chunks from start state, writing exact
//      state into zs[h] ONLY for h%4==3 (the only states kC reads now).
// ---------------------------------------------------------------------------
__global__ __launch_bounds__(64) void kB1_fold(
        const float* __restrict__ A, const float* __restrict__ zs,
        float* __restrict__ E) {
    int seg = blockIdx.x / SGRP;
    int s = (blockIdx.x % SGRP) * 64 + threadIdx.x;
    if (s >= NSEQ) return;
    int c = s % NCH;
    float a1 = A[c * 5 + 1], a2 = A[c * 5 + 2], a3 = A[c * 5 + 3], a4 = A[c * 5 + 4];
    MDECL(M1); BUILD_M64(M1, a1, a2, a3, a4);
    const float4* zb = (const float4*)zs;
    float4 e = make_float4(0.f, 0.f, 0.f, 0.f);
    size_t base = (size_t)seg * LSEG * NSEQ + s;
    #pragma unroll 5
    for (int i = 0; i < LSEG; ++i) {
        float4 d = zb[base + (size_t)i * NSEQ];
        AFF_STEP(M1, e, d);
    }
    ((float4*)E)[(size_t)seg * NSEQ + s] = e;
}

__global__ __launch_bounds__(64) void kB2_carry(
        const float* __restrict__ A, float* __restrict__ E) {
    int s = blockIdx.x * 64 + threadIdx.x;
    if (s >= NSEQ) return;
    int c = s % NCH;
    float a1 = A[c * 5 + 1], a2 = A[c * 5 + 2], a3 = A[c * 5 + 3], a4 = A[c * 5 + 4];
    MDECL(M1); BUILD_M64(M1, a1, a2, a3, a4);
    // ML = M1^25 = M1^16 * M1^8 * M1
    MDECL(P8);
    { MDECL(T); MMUL(T, M1, M1); MDECL(P4); MMUL(P4, T, T); MMUL(P8, P4, P4); }
    MDECL(ML);
    { MDECL(P16); MMUL(P16, P8, P8); MDECL(P24); MMUL(P24, P16, P8);
      MMUL(ML, P24, M1); }
    float4* E4 = (float4*)E;
    float4 Z = make_float4(0.f, 0.f, 0.f, 0.f);
    float4 Eseg = E4[s];                       // prefetch seg 0
    #pragma unroll 4
    for (int seg = 0; seg < SEG; ++seg) {
        float4 Enext;
        if (seg + 1 < SEG) Enext = E4[(size_t)(seg + 1) * NSEQ + s];
        else               Enext = Z;
        E4[(size_t)seg * NSEQ + s] = Z;        // exclusive segment-start state
        AFF_STEP(ML, Z, Eseg);
        Eseg = Enext;
    }
}

__global__ __launch_bounds__(64) void kB3_replay(
        const float* __restrict__ A, float* __restrict__ zs,
        const float* __restrict__ E) {
    int seg = blockIdx.x / SGRP;
    int s = (blockIdx.x % SGRP) * 64 + threadIdx.x;
    if (s >= NSEQ) return;
    int c = s % NCH;
    float a1 = A[c * 5 + 1], a2 = A[c * 5 + 2], a3 = A[c * 5 + 3], a4 = A[c * 5 + 4];
    MDECL(M1); BUILD_M64(M1, a1, a2, a3, a4);
    float4* zb = (float4*)zs;
    float4 z = ((const float4*)E)[(size_t)seg * NSEQ + s];
    int h0 = seg * LSEG;
    #pragma unroll 5
    for (int i = 0; i < LSEG; ++i) {
        size_t ix = (size_t)(h0 + i) * NSEQ + s;
        float4 d = zb[ix];             // read forced response BEFORE overwrite
        if (((h0 + i) & 3) == 3) zb[ix] = z;   // exact state; only h%4==3 consumed
        AFF_STEP(M1, z, d);
    }
}

// ---------------------------------------------------------------------------
// Kernel C: FULL-FRAME tiles (256 samples), 256-thr blocks (4 tiles/block).
// Tile r in [0, NFRM) covers samples [256r, 256r+256) = frame r.
// Warm-up: 64 WSTEPs over [256r-64, 256r) from the EXACT state zs[4r-1]
// (beta^64 = 3.4e-4 u-truncation, z exact — same truncation as TILE=128,
// but the fixed 64-step warm tax is amortized over 256 main steps instead
// of 128: 320 steps/frame vs 384 = 17% less work).
// Each frame emits its full alpha-fold G (single buffer) + y4f at j=0.
// Blocks [0, KC_EDGE): channel-128 path, one (b,r) item per thread.
// Blocks [KC_EDGE, +KC_MAIN): pair-channel main, wave w -> tile blk*4+w;
// lane t runs packed chains {2t,2t+1}; shfl consumed one step late.
// ---------------------------------------------------------------------------
__global__ __launch_bounds__(256, 8) void kC_main(
        const float* __restrict__ wav, const float* __restrict__ B,
        const float* __restrict__ A, const float* __restrict__ zs,
        float* __restrict__ G, float* __restrict__ y4f,
        float beta, float alpha) {
    __shared__ float4 xs4[4 * 80];   // per-wave up to 80-float4 segments
    int blk = blockIdx.x;
    const f2 beta2 = mk2(beta, beta);
    const f2 alpha2 = mk2(alpha, alpha);

    if (blk < KC_EDGE) {
        // ---- edge: channel 128, one (b,r) per thread ----
        int item = blk * 256 + threadIdx.x;
        if (item >= NBK) return;
        int b = item / NFRM;
        int r = item - b * NFRM;
        C2 q = load_coef2(B, A, 127, 128);
        f2 z0 = mk2(0.f, 0.f), z1 = z0, z2 = z0, z3 = z0, u = z0;
        const float* xg;
        if (r > 0) {
            float4 vx = ((const float4*)zs)[SEQ4(4 * r - 1, b, 127)];
            float4 vy = ((const float4*)zs)[SEQ4(4 * r - 1, b, 128)];
            z0 = mk2(vx.x, vy.x); z1 = mk2(vx.y, vy.y);
            z2 = mk2(vx.z, vy.z); z3 = mk2(vx.w, vy.w);
            xg = wav + (size_t)b * TLEN + (size_t)(4 * r - 1) * CHUNK;
            #pragma unroll 2
            for (int j = 0; j < CHUNK; ++j) WSTEP(xg[j]);
            xg += CHUNK;
        } else {
            xg = wav + (size_t)b * TLEN;
        }
        float g4 = 0.f, yfirst = 0.f;
        #pragma unroll 2
        for (int j = 0; j < TILE; ++j) {
            f2 y_ = iir2_step(q, xg[j], z0, z1, z2, z3);
            u = fma2(beta2, u, sig2(y_));
            float y4 = fmaxf(u.y - u.x, 0.0f);   // ch128 - ch127
            if (j == 0) yfirst = y4;
            g4 = fmaf(alpha, g4, y4);
        }
        size_t idx = ((size_t)b * NFRM + r) * NCH + 128;
        G[idx] = g4;
        y4f[idx] = yfirst;
        return;
    }

    // ---- main: wave w handles frame-tile (blk-KC_EDGE)*4 + w ----
    int wave = threadIdx.x >> 6;
    int t = threadIdx.x & 63;                // lane 0..63
    int tile = (blk - KC_EDGE) * 4 + wave;   // b * NFRM + r, < NBK
    int b = tile / NFRM;
    int r = tile - b * NFRM;
    int n4 = (r > 0) ? 80 : 64;              // (64 warm + 256 main) or 256
    int gend = n4;
    const float* xg = wav + (size_t)b * TLEN +
                      ((r > 0) ? (size_t)(4 * r - 1) * CHUNK : (size_t)0);
    float4* seg = xs4 + wave * 80;
    for (int i = t; i < n4; i += 64) seg[i] = ((const float4*)xg)[i];
    __syncthreads();

    int cA = 2 * t, cB = 2 * t + 1;          // chains (cB <= 127)
    C2 q = load_coef2(B, A, cA, cB);
    f2 z0 = mk2(0.f, 0.f), z1 = z0, z2 = z0, z3 = z0, u = z0;
    int gbase = 0;
    if (r > 0) {
        // coalesced: wave reads c = 0..127 consecutive float4s
        float4 vx = ((const float4*)zs)[SEQ4(4 * r - 1, b, cA)];
        float4 vy = ((const float4*)zs)[SEQ4(4 * r - 1, b, cB)];
        z0 = mk2(vx.x, vy.x); z1 = mk2(vx.y, vy.y);
        z2 = mk2(vx.z, vy.z); z3 = mk2(vx.w, vy.w);
        for (int g = 0; g < CHUNK / 4; ++g) {      // 16 groups = 64 warm steps
            float4 xq = seg[g];
            WSTEP(xq.x); WSTEP(xq.y); WSTEP(xq.z); WSTEP(xq.w);
        }
        gbase = CHUNK / 4;
    }

    // main 256 steps; pipeline: ge consumes shfl one step late.
    f2 g2;
    float fo, fe, pend_un, pend_ub;
    {   // first group: peel j=0 and j=1
        float4 xq = seg[gbase];
        // j = 0
        f2 y_ = iir2_step(q, xq.x, z0, z1, z2, z3);
        u = fma2(beta2, u, sig2(y_));
        float un_ = __shfl_down(u.x, 1, 64);
        float y4o_ = fmaxf(u.y - u.x, 0.0f);
        fo = y4o_;
        g2 = mk2(y4o_, 0.0f);
        pend_un = un_; pend_ub = u.y;
        // j = 1
        y_ = iir2_step(q, xq.y, z0, z1, z2, z3);
        u = fma2(beta2, u, sig2(y_));
        un_ = __shfl_down(u.x, 1, 64);
        y4o_ = fmaxf(u.y - u.x, 0.0f);
        float y4e_ = fmaxf(pend_un - pend_ub, 0.0f);
        fe = y4e_;                            // y4e at j=0
        g2 = fma2(alpha2, g2, mk2(y4o_, y4e_));
        pend_un = un_; pend_ub = u.y;
        // j = 2, 3
        MSTEP(xq.z); MSTEP(xq.w);
    }
    for (int g = gbase + 1; g < gbase + TILE / 4; ++g) {
        float4 xq = seg[g];
        MSTEP(xq.x); MSTEP(xq.y); MSTEP(xq.z); MSTEP(xq.w);
    }
    (void)gend;
    // tail: apply the last pending ge term
    float y4e_last = fmaxf(pend_un - pend_ub, 0.0f);
    float go = g2.x;
    float ge = fmaf(alpha, g2.y, y4e_last);

    size_t base = ((size_t)b * NFRM + r) * NCH;
    G[base + cB] = go;             // channel 2t+1 (odd 1..127)
    y4f[base + cB] = fo;
    if (t < 63) {
        G[base + cB + 1] = ge;     // channel 2t+2 (even 2..126)
        y4f[base + cB + 1] = fe;
    }
}

// ---------------------------------------------------------------------------
// Kernel D: PARALLEL alpha-scan per (b,c) — one wave per sequence.
// Lane l owns frames [4l, 4l+4) (256 >= NFRM=250, padded g=0).
//   o[k] = alpha * s_in[k] + y4f[k];  s' = aL*s + G[k]  (full-frame fold).
// Kogge-Stone over lanes with scalar factor (aL^4)^{2^s}.
// ---------------------------------------------------------------------------
#define KD_LOAD(gn, yn, i)                                                     \
    {   int kk = k0 + (i); int kcl = (kk < NFRM) ? kk : (NFRM - 1);            \
        size_t ix = ((size_t)b * NFRM + kcl) * NCH + c;                        \
        gn = G[ix]; yn = y4f[ix];                                              \
        if (kk >= NFRM) { gn = 0.f; yn = 0.f; } }
#define KD_REPLAY(gn, yn, i)                                                   \
    {   int kk = k0 + (i);                                                     \
        if (kk < NFRM) o[kk] = fmaf(alpha, sv, yn);                            \
        sv = fmaf(aL, sv, gn); }

__global__ __launch_bounds__(256) void kD_scan_par(
        const float* __restrict__ G, const float* __restrict__ y4f,
        float* __restrict__ out, float alpha, float aL) {
    int id = blockIdx.x * 4 + (threadIdx.x >> 6);   // b * NCH + c
    int lane = threadIdx.x & 63;
    if (id >= NSEQ) return;
    int b = id / NCH;
    int c = id - b * NCH;
    float* o = out + (size_t)id * NFRM;
    int k0 = lane * 4;
    if (c == 0) {
        #pragma unroll
        for (int i = 0; i < 4; ++i) {
            int kk = k0 + i;
            if (kk < NFRM) o[kk] = 0.0f;
        }
        return;
    }
    float g0, g1, g2v, g3, y0, y1, y2v, y3;
    KD_LOAD(g0, y0, 0); KD_LOAD(g1, y1, 1); KD_LOAD(g2v, y2v, 2); KD_LOAD(g3, y3, 3);
    // local inclusive carry
    float e = g0;
    e = fmaf(aL, e, g1);
    e = fmaf(aL, e, g2v);
    e = fmaf(aL, e, g3);
    // Kogge-Stone with factor f = (aL^4)^{2^s}
    float aL2 = aL * aL;
    float f = aL2 * aL2;                     // aL^4
    for (int s = 0; s < 6; ++s) {
        int off = 1 << s;
        float src = __shfl_up(e, off, 64);
        if (lane < off) src = 0.f;
        e = fmaf(f, src, e);
        f = f * f;
    }
    // exclusive shift
    float sv = __shfl_up(e, 1, 64);
    if (lane == 0) sv = 0.f;
    // replay + store
    KD_REPLAY(g0, y0, 0); KD_REPLAY(g1, y1, 1);
    KD_REPLAY(g2v, y2v, 2); KD_REPLAY(g3, y3, 3);
}

// ---------------------------------------------------------------------------
extern "C" void kernel_launch(void* const* d_in, const int* in_sizes, int n_in,
                              void* d_out, int out_size, void* d_ws, size_t ws_size,
                              hipStream_t stream) {
    const float* wav = (const float*)d_in[0];   // (BS, TLEN)
    const float* Bc  = (const float*)d_in[1];   // (NCH, 5)
    const float* Ac  = (const float*)d_in[2];   // (NCH, 5)
    float* out = (float*)d_out;                 // (BS, NCH, NFRM)

    // workspace: zs (NH*NSEQ float4 = 16.5 MB) | G | y4f (1.03 MB each)
    //            | E (SEG*NSEQ float4 = 660 KB)
    float* zs  = (float*)d_ws;
    float* G   = zs + (size_t)NH * NSEQ * 4;
    float* y4f = G + (size_t)NBK * NCH;
    float* E   = y4f + (size_t)NBK * NCH;

    const float alpha  = (float)exp(-1.0 / 128.0);
    const float beta   = (float)exp(-1.0 / 8.0);
    const float alphaL = (float)exp(-256.0 / 128.0);   // alpha^256 (frame step)

    kA_forced_state<<<KA_EDGE + NT, 128, 0, stream>>>(wav, Bc, Ac, zs);
    kB1_fold<<<SEG * SGRP, 64, 0, stream>>>(Ac, zs, E);
    kB2_carry<<<SGRP, 64, 0, stream>>>(Ac, E);
    kB3_replay<<<SEG * SGRP, 64, 0, stream>>>(Ac, zs, E);
    kC_main<<<KC_EDGE + KC_MAIN, 256, 0, stream>>>(wav, Bc, Ac, zs, G, y4f, beta, alpha);
    kD_scan_par<<<NSEQ / 4, 256, 0, stream>>>(G, y4f, out, alpha, alphaL);
}

// Round 7
// 132.558 us; speedup vs baseline: 1.2893x; 1.0451x over previous
//
#include <hip/hip_runtime.h>
#include <math.h>

// Problem constants (from reference)
#define NCH 129
#define BS 8
#define TLEN 64000
#define CHUNK 256         // state granularity == frame length now
#define WARM 64           // kC warm-up length (samples before frame start)
#define NH 250            // TLEN / CHUNK state chunks (== NFRM)
#define TILE 256          // kC tile length (one FULL frame)
#define LFRM 256          // frame stride
#define NFRM 250          // number of frames
#define NSEQ (NCH * BS)   // 1032 sequences
#define NBK (BS * NFRM)   // 2000 (b,frame) cells
#define NT (BS * NH)      // 2000 (b,chunk) items (kernel A)
#define KA_EDGE 16        // ceil(NT/128): kA channel-128 blocks
#define KC_EDGE 8         // ceil(NBK/256): kC channel-128 blocks
#define KC_MAIN (NBK / 4) // 500 main blocks (4 frame-tiles per 256-thr block)
#define SEG 25            // kB segments
#define LSEG 10           // chunks per segment (SEG*LSEG == NH)
#define SGRP 17           // ceil(NSEQ/64) sequence groups per segment

// float4 index of state-chunk h, batch b, channel c.  Layout [h][b][c]:
// c fastest -> kA writes (c = tid) and kC reads (c = 2t,2t+1) are coalesced.
#define SEQ4(h, b, c) ((size_t)(h) * NSEQ + (size_t)(b) * NCH + (c))

typedef float f2 __attribute__((ext_vector_type(2)));

__device__ __forceinline__ f2 mk2(float a, float b) { f2 r; r.x = a; r.y = b; return r; }

__device__ __forceinline__ f2 fma2(f2 a, f2 b, f2 c) {
#if __has_builtin(__builtin_elementwise_fma)
    return __builtin_elementwise_fma(a, b, c);
#else
    f2 r; r.x = fmaf(a.x, b.x, c.x); r.y = fmaf(a.y, b.y, c.y); return r;
#endif
}

__device__ __forceinline__ f2 sig2(f2 v) {
    f2 r;
    r.x = __builtin_amdgcn_rcpf(1.0f + __expf(-v.x));
    r.y = __builtin_amdgcn_rcpf(1.0f + __expf(-v.y));
    return r;
}

// Packed pair-of-chains coefficients.
struct C2 { f2 b0, b1, b2, b3, b4, a1, a2, a3, a4; };

__device__ __forceinline__ C2 load_coef2(const float* __restrict__ B,
                                         const float* __restrict__ A,
                                         int cx, int cy) {
    C2 q;
    q.b0 = mk2(B[cx * 5 + 0], B[cy * 5 + 0]);
    q.b1 = mk2(B[cx * 5 + 1], B[cy * 5 + 1]);
    q.b2 = mk2(B[cx * 5 + 2], B[cy * 5 + 2]);
    q.b3 = mk2(B[cx * 5 + 3], B[cy * 5 + 3]);
    q.b4 = mk2(B[cx * 5 + 4], B[cy * 5 + 4]);
    q.a1 = mk2(A[cx * 5 + 1], A[cy * 5 + 1]);
    q.a2 = mk2(A[cx * 5 + 2], A[cy * 5 + 2]);
    q.a3 = mk2(A[cx * 5 + 3], A[cy * 5 + 3]);
    q.a4 = mk2(A[cx * 5 + 4], A[cy * 5 + 4]);
    return q;
}

__device__ __forceinline__ f2 iir2_step(const C2& q, float x,
                                        f2& z0, f2& z1, f2& z2, f2& z3) {
    f2 xx = mk2(x, x);
    f2 y = fma2(q.b0, xx, z0);
    z0 = fma2(-q.a1, y, fma2(q.b1, xx, z1));
    z1 = fma2(-q.a2, y, fma2(q.b2, xx, z2));
    z2 = fma2(-q.a3, y, fma2(q.b3, xx, z3));
    z3 = fma2(-q.a4, y, q.b4 * xx);
    return y;
}

// Scalar variants (kernel A only).
struct Coef { float b0, b1, b2, b3, b4, a1, a2, a3, a4; };
__device__ __forceinline__ Coef load_coef(const float* __restrict__ B,
                                          const float* __restrict__ A, int c) {
    Coef q;
    q.b0 = B[c * 5 + 0]; q.b1 = B[c * 5 + 1]; q.b2 = B[c * 5 + 2];
    q.b3 = B[c * 5 + 3]; q.b4 = B[c * 5 + 4];
    q.a1 = A[c * 5 + 1]; q.a2 = A[c * 5 + 2];
    q.a3 = A[c * 5 + 3]; q.a4 = A[c * 5 + 4];
    return q;
}
__device__ __forceinline__ float iir_step(const Coef& q, float x,
                                          float& z0, float& z1, float& z2, float& z3) {
    float y = fmaf(q.b0, x, z0);
    z0 = fmaf(-q.a1, y, fmaf(q.b1, x, z1));
    z1 = fmaf(-q.a2, y, fmaf(q.b2, x, z2));
    z2 = fmaf(-q.a3, y, fmaf(q.b3, x, z3));
    z3 = fmaf(-q.a4, y, q.b4 * x);
    return y;
}

// step macros for packed chains (coef struct must be named q)
#define WSTEP(xv)                                                              \
    { f2 y_ = iir2_step(q, (xv), z0, z1, z2, z3);                              \
      u = fma2(beta2, u, sig2(y_)); }
#define MSTEP(xv)                                                              \
    { f2 y_ = iir2_step(q, (xv), z0, z1, z2, z3);                              \
      u = fma2(beta2, u, sig2(y_));                                            \
      float un_ = __shfl_down(u.x, 1, 64);                                     \
      float y4o_ = fmaxf(u.y - u.x, 0.0f);                                     \
      float y4e_ = fmaxf(pend_un - pend_ub, 0.0f);                             \
      g2 = fma2(alpha2, g2, mk2(y4o_, y4e_));                                  \
      pend_un = un_; pend_ub = u.y; }

// ---- 4x4 matrix helpers over 16 NAMED scalars (no arrays -> no scratch) ----
#define MDECL(X) float X##00, X##01, X##02, X##03, X##10, X##11, X##12, X##13, \
                       X##20, X##21, X##22, X##23, X##30, X##31, X##32, X##33
#define MCOPY(D, S) D##00=S##00; D##01=S##01; D##02=S##02; D##03=S##03;        \
                    D##10=S##10; D##11=S##11; D##12=S##12; D##13=S##13;        \
                    D##20=S##20; D##21=S##21; D##22=S##22; D##23=S##23;        \
                    D##30=S##30; D##31=S##31; D##32=S##32; D##33=S##33
#define MROW(R, X, Y, i)                                                       \
    R##i##0 = fmaf(X##i##0, Y##00, fmaf(X##i##1, Y##10, fmaf(X##i##2, Y##20, X##i##3 * Y##30))); \
    R##i##1 = fmaf(X##i##0, Y##01, fmaf(X##i##1, Y##11, fmaf(X##i##2, Y##21, X##i##3 * Y##31))); \
    R##i##2 = fmaf(X##i##0, Y##02, fmaf(X##i##1, Y##12, fmaf(X##i##2, Y##22, X##i##3 * Y##32))); \
    R##i##3 = fmaf(X##i##0, Y##03, fmaf(X##i##1, Y##13, fmaf(X##i##2, Y##23, X##i##3 * Y##33)))
#define MMUL(R, X, Y) MROW(R, X, Y, 0); MROW(R, X, Y, 1); MROW(R, X, Y, 2); MROW(R, X, Y, 3)
// r (float4) = X * v (float4)
#define MV(r, X, v)                                                            \
    r.x = fmaf(X##00, v.x, fmaf(X##01, v.y, fmaf(X##02, v.z, X##03 * v.w)));   \
    r.y = fmaf(X##10, v.x, fmaf(X##11, v.y, fmaf(X##12, v.z, X##13 * v.w)));   \
    r.z = fmaf(X##20, v.x, fmaf(X##21, v.y, fmaf(X##22, v.z, X##23 * v.w)));   \
    r.w = fmaf(X##30, v.x, fmaf(X##31, v.y, fmaf(X##32, v.z, X##33 * v.w)))
// build companion matrix M and raise to M^(2^NSQ) via NSQ squarings
#define BUILD_MPOW(M1, a1, a2, a3, a4, NSQ)                                    \
    M1##00 = -(a1); M1##01 = 1.f; M1##02 = 0.f; M1##03 = 0.f;                  \
    M1##10 = -(a2); M1##11 = 0.f; M1##12 = 1.f; M1##13 = 0.f;                  \
    M1##20 = -(a3); M1##21 = 0.f; M1##22 = 0.f; M1##23 = 1.f;                  \
    M1##30 = -(a4); M1##31 = 0.f; M1##32 = 0.f; M1##33 = 0.f;                  \
    for (int s_ = 0; s_ < (NSQ); ++s_) { MDECL(T_); MMUL(T_, M1, M1); MCOPY(M1, T_); }

// affine step helper: e = M*e + d
#define AFF_STEP(M, e, d)                                                      \
    {   float4 t_; MV(t_, M, e);                                               \
        e.x = t_.x + d.x; e.y = t_.y + d.y;                                    \
        e.z = t_.z + d.z; e.w = t_.w + d.w; }

// ---------------------------------------------------------------------------
// Kernel A: forced response per (c, b, 256-chunk h) from zero state.
// Writes TWO snapshots per chunk: W[h] = state after 192 samples (the warm
// start for frame h+1 lives at sample 256h+192 = 256(h+1)-64) and
// D[h] = state after all 256 samples (the scan increment).
// Blocks [0, KA_EDGE): channel 128 — one (b,h) item per thread.
// Blocks [KA_EDGE, +NT): channels 0..127 — 128 threads, LDS-staged x.
// ---------------------------------------------------------------------------
__global__ __launch_bounds__(128, 8) void kA_forced_state(
        const float* __restrict__ wav, const float* __restrict__ B,
        const float* __restrict__ A, float* __restrict__ D,
        float* __restrict__ W) {
    __shared__ float xs[CHUNK];
    int blk = blockIdx.x;
    if (blk < KA_EDGE) {
        int item = blk * 128 + threadIdx.x;
        if (item >= NT) return;
        int b = item / NH;
        int h = item - b * NH;
        const float* xg = wav + (size_t)b * TLEN + (size_t)h * CHUNK;
        Coef q = load_coef(B, A, 128);
        float z0 = 0.f, z1 = 0.f, z2 = 0.f, z3 = 0.f;
        #pragma unroll 4
        for (int j = 0; j < CHUNK - WARM; ++j) {
            (void)iir_step(q, xg[j], z0, z1, z2, z3);
        }
        ((float4*)W)[SEQ4(h, b, 128)] = make_float4(z0, z1, z2, z3);
        #pragma unroll 4
        for (int j = CHUNK - WARM; j < CHUNK; ++j) {
            (void)iir_step(q, xg[j], z0, z1, z2, z3);
        }
        ((float4*)D)[SEQ4(h, b, 128)] = make_float4(z0, z1, z2, z3);
        return;
    }
    int mblk = blk - KA_EDGE;        // b * NH + h
    int b = mblk / NH;
    int h = mblk - b * NH;
    const float* xg = wav + (size_t)b * TLEN + (size_t)h * CHUNK;
    xs[threadIdx.x] = xg[threadIdx.x];
    xs[threadIdx.x + 128] = xg[threadIdx.x + 128];
    __syncthreads();
    int c = threadIdx.x;             // 0..127
    Coef q = load_coef(B, A, c);
    float z0 = 0.f, z1 = 0.f, z2 = 0.f, z3 = 0.f;
    #pragma unroll 8
    for (int j = 0; j < CHUNK - WARM; ++j) {
        (void)iir_step(q, xs[j], z0, z1, z2, z3);
    }
    ((float4*)W)[SEQ4(h, b, c)] = make_float4(z0, z1, z2, z3);   // coalesced in c
    #pragma unroll 8
    for (int j = CHUNK - WARM; j < CHUNK; ++j) {
        (void)iir_step(q, xs[j], z0, z1, z2, z3);
    }
    ((float4*)D)[SEQ4(h, b, c)] = make_float4(z0, z1, z2, z3);
}

// ---------------------------------------------------------------------------
// Kernel B (3-pass segmented affine scan over 256-chunks, lane-coalesced).
// Sequence id s = b*NCH + c; lanes span consecutive s -> 1 KB transactions.
// kB1: E[seg][s] = fold of segment's 10 D's with M256.
// kB2: serial scan over 25 segment carries with ML = M256^10 (prefetched);
//      overwrites E[seg][s] with the EXCLUSIVE segment-start state.
// kB3: replay 10 chunks per segment; for each h writes the WARM-START
//      state  ZW[h] = M192 * z_in[h] + W[h]  (= exact state at 256h+192),
//      then advances z_in via M256 and D[h]. ZW is all kC reads.
// ---------------------------------------------------------------------------
__global__ __launch_bounds__(64) void kB1_fold(
        const float* __restrict__ A, const float* __restrict__ D,
        float* __restrict__ E) {
    int seg = blockIdx.x / SGRP;
    int s = (blockIdx.x % SGRP) * 64 + threadIdx.x;
    if (s >= NSEQ) return;
    int c = s % NCH;
    float a1 = A[c * 5 + 1], a2 = A[c * 5 + 2], a3 = A[c * 5 + 3], a4 = A[c * 5 + 4];
    MDECL(M1); BUILD_MPOW(M1, a1, a2, a3, a4, 8);   // M^256
    const float4* db = (const float4*)D;
    float4 e = make_float4(0.f, 0.f, 0.f, 0.f);
    size_t base = (size_t)seg * LSEG * NSEQ + s;
    #pragma unroll
    for (int i = 0; i < LSEG; ++i) {
        float4 d = db[base + (size_t)i * NSEQ];
        AFF_STEP(M1, e, d);
    }
    ((float4*)E)[(size_t)seg * NSEQ + s] = e;
}

__global__ __launch_bounds__(64) void kB2_carry(
        const float* __restrict__ A, float* __restrict__ E) {
    int s = blockIdx.x * 64 + threadIdx.x;
    if (s >= NSEQ) return;
    int c = s % NCH;
    float a1 = A[c * 5 + 1], a2 = A[c * 5 + 2], a3 = A[c * 5 + 3], a4 = A[c * 5 + 4];
    MDECL(M1); BUILD_MPOW(M1, a1, a2, a3, a4, 8);   // M^256
    // ML = M256^10 = P8 * P2  (P2 = M256^2, P4, P8 by squaring)
    MDECL(P2); MMUL(P2, M1, M1);
    MDECL(P4); MMUL(P4, P2, P2);
    MDECL(P8); MMUL(P8, P4, P4);
    MDECL(ML); MMUL(ML, P8, P2);
    float4* E4 = (float4*)E;
    float4 Z = make_float4(0.f, 0.f, 0.f, 0.f);
    float4 Eseg = E4[s];                       // prefetch seg 0
    for (int seg = 0; seg < SEG; ++seg) {
        float4 Enext;
        if (seg + 1 < SEG) Enext = E4[(size_t)(seg + 1) * NSEQ + s];
        else               Enext = Z;
        E4[(size_t)seg * NSEQ + s] = Z;        // exclusive segment-start state
        AFF_STEP(ML, Z, Eseg);
        Eseg = Enext;
    }
}

__global__ __launch_bounds__(64) void kB3_replay(
        const float* __restrict__ A, const float* __restrict__ D,
        const float* __restrict__ W, float* __restrict__ ZW,
        const float* __restrict__ E) {
    int seg = blockIdx.x / SGRP;
    int s = (blockIdx.x % SGRP) * 64 + threadIdx.x;
    if (s >= NSEQ) return;
    int c = s % NCH;
    float a1 = A[c * 5 + 1], a2 = A[c * 5 + 2], a3 = A[c * 5 + 3], a4 = A[c * 5 + 4];
    MDECL(M64); BUILD_MPOW(M64, a1, a2, a3, a4, 6);  // M^64
    MDECL(M128); MMUL(M128, M64, M64);               // M^128
    MDECL(M192); MMUL(M192, M128, M64);              // M^192
    MDECL(M256); MMUL(M256, M128, M128);             // M^256
    const float4* db = (const float4*)D;
    const float4* wb = (const float4*)W;
    float4* zwb = (float4*)ZW;
    float4 z = ((const float4*)E)[(size_t)seg * NSEQ + s];
    int h0 = seg * LSEG;
    #pragma unroll
    for (int i = 0; i < LSEG; ++i) {
        size_t ix = (size_t)(h0 + i) * NSEQ + s;
        float4 d = db[ix];
        float4 w = wb[ix];
        float4 zw; MV(zw, M192, z);
        zw.x += w.x; zw.y += w.y; zw.z += w.z; zw.w += w.w;
        zwb[ix] = zw;                // exact state at sample 256h+192
        AFF_STEP(M256, z, d);        // advance to next chunk boundary
    }
}

// ---------------------------------------------------------------------------
// Kernel C: FULL-FRAME tiles (256 samples), 256-thr blocks (4 tiles/block).
// Tile r covers frame r = samples [256r, 256r+256). Warm-up: 64 WSTEPs over
// [256r-64, 256r) from the EXACT state ZW[r-1] (beta^64 u-truncation).
// Blocks [0, KC_EDGE): channel-128 path, one (b,r) item per thread.
// Blocks [KC_EDGE, +KC_MAIN): pair-channel main, wave w -> tile blk*4+w;
// lane t runs packed chains {2t,2t+1}; shfl consumed one step late.
// ---------------------------------------------------------------------------
__global__ __launch_bounds__(256, 8) void kC_main(
        const float* __restrict__ wav, const float* __restrict__ B,
        const float* __restrict__ A, const float* __restrict__ ZW,
        float* __restrict__ G, float* __restrict__ y4f,
        float beta, float alpha) {
    __shared__ float4 xs4[4 * 80];   // per-wave up to 80-float4 segments
    int blk = blockIdx.x;
    const f2 beta2 = mk2(beta, beta);
    const f2 alpha2 = mk2(alpha, alpha);

    if (blk < KC_EDGE) {
        // ---- edge: channel 128, one (b,r) per thread ----
        int item = blk * 256 + threadIdx.x;
        if (item >= NBK) return;
        int b = item / NFRM;
        int r = item - b * NFRM;
        C2 q = load_coef2(B, A, 127, 128);
        f2 z0 = mk2(0.f, 0.f), z1 = z0, z2 = z0, z3 = z0, u = z0;
        const float* xg;
        if (r > 0) {
            float4 vx = ((const float4*)ZW)[SEQ4(r - 1, b, 127)];
            float4 vy = ((const float4*)ZW)[SEQ4(r - 1, b, 128)];
            z0 = mk2(vx.x, vy.x); z1 = mk2(vx.y, vy.y);
            z2 = mk2(vx.z, vy.z); z3 = mk2(vx.w, vy.w);
            xg = wav + (size_t)b * TLEN + (size_t)r * TILE - WARM;
            #pragma unroll 2
            for (int j = 0; j < WARM; ++j) WSTEP(xg[j]);
            xg += WARM;
        } else {
            xg = wav + (size_t)b * TLEN;
        }
        float g4 = 0.f, yfirst = 0.f;
        #pragma unroll 2
        for (int j = 0; j < TILE; ++j) {
            f2 y_ = iir2_step(q, xg[j], z0, z1, z2, z3);
            u = fma2(beta2, u, sig2(y_));
            float y4 = fmaxf(u.y - u.x, 0.0f);   // ch128 - ch127
            if (j == 0) yfirst = y4;
            g4 = fmaf(alpha, g4, y4);
        }
        size_t idx = ((size_t)b * NFRM + r) * NCH + 128;
        G[idx] = g4;
        y4f[idx] = yfirst;
        return;
    }

    // ---- main: wave w handles frame-tile (blk-KC_EDGE)*4 + w ----
    int wave = threadIdx.x >> 6;
    int t = threadIdx.x & 63;                // lane 0..63
    int tile = (blk - KC_EDGE) * 4 + wave;   // b * NFRM + r, < NBK
    int b = tile / NFRM;
    int r = tile - b * NFRM;
    int n4 = (r > 0) ? 80 : 64;              // (64 warm + 256 main) or 256
    const float* xg = wav + (size_t)b * TLEN +
                      ((r > 0) ? (size_t)r * TILE - WARM : (size_t)0);
    float4* seg = xs4 + wave * 80;
    for (int i = t; i < n4; i += 64) seg[i] = ((const float4*)xg)[i];
    __syncthreads();

    int cA = 2 * t, cB = 2 * t + 1;          // chains (cB <= 127)
    C2 q = load_coef2(B, A, cA, cB);
    f2 z0 = mk2(0.f, 0.f), z1 = z0, z2 = z0, z3 = z0, u = z0;
    int gbase = 0;
    if (r > 0) {
        // coalesced: wave reads c = 0..127 consecutive float4s
        float4 vx = ((const float4*)ZW)[SEQ4(r - 1, b, cA)];
        float4 vy = ((const float4*)ZW)[SEQ4(r - 1, b, cB)];
        z0 = mk2(vx.x, vy.x); z1 = mk2(vx.y, vy.y);
        z2 = mk2(vx.z, vy.z); z3 = mk2(vx.w, vy.w);
        for (int g = 0; g < WARM / 4; ++g) {       // 16 groups = 64 warm steps
            float4 xq = seg[g];
            WSTEP(xq.x); WSTEP(xq.y); WSTEP(xq.z); WSTEP(xq.w);
        }
        gbase = WARM / 4;
    }

    // main 256 steps; pipeline: ge consumes shfl one step late.
    f2 g2;
    float fo, fe, pend_un, pend_ub;
    {   // first group: peel j=0 and j=1
        float4 xq = seg[gbase];
        // j = 0
        f2 y_ = iir2_step(q, xq.x, z0, z1, z2, z3);
        u = fma2(beta2, u, sig2(y_));
        float un_ = __shfl_down(u.x, 1, 64);
        float y4o_ = fmaxf(u.y - u.x, 0.0f);
        fo = y4o_;
        g2 = mk2(y4o_, 0.0f);
        pend_un = un_; pend_ub = u.y;
        // j = 1
        y_ = iir2_step(q, xq.y, z0, z1, z2, z3);
        u = fma2(beta2, u, sig2(y_));
        un_ = __shfl_down(u.x, 1, 64);
        y4o_ = fmaxf(u.y - u.x, 0.0f);
        float y4e_ = fmaxf(pend_un - pend_ub, 0.0f);
        fe = y4e_;                            // y4e at j=0
        g2 = fma2(alpha2, g2, mk2(y4o_, y4e_));
        pend_un = un_; pend_ub = u.y;
        // j = 2, 3
        MSTEP(xq.z); MSTEP(xq.w);
    }
    for (int g = gbase + 1; g < gbase + TILE / 4; ++g) {
        float4 xq = seg[g];
        MSTEP(xq.x); MSTEP(xq.y); MSTEP(xq.z); MSTEP(xq.w);
    }
    // tail: apply the last pending ge term
    float y4e_last = fmaxf(pend_un - pend_ub, 0.0f);
    float go = g2.x;
    float ge = fmaf(alpha, g2.y, y4e_last);

    size_t base = ((size_t)b * NFRM + r) * NCH;
    G[base + cB] = go;             // channel 2t+1 (odd 1..127)
    y4f[base + cB] = fo;
    if (t < 63) {
        G[base + cB + 1] = ge;     // channel 2t+2 (even 2..126)
        y4f[base + cB + 1] = fe;
    }
}

// ---------------------------------------------------------------------------
// Kernel D: PARALLEL alpha-scan per (b,c) — one wave per sequence.
// Lane l owns frames [4l, 4l+4) (256 >= NFRM=250, padded g=0).
//   o[k] = alpha * s_in[k] + y4f[k];  s' = aL*s + G[k]  (full-frame fold).
// Kogge-Stone over lanes with scalar factor (aL^4)^{2^s}.
// ---------------------------------------------------------------------------
#define KD_LOAD(gn, yn, i)                                                     \
    {   int kk = k0 + (i); int kcl = (kk < NFRM) ? kk : (NFRM - 1);            \
        size_t ix = ((size_t)b * NFRM + kcl) * NCH + c;                        \
        gn = G[ix]; yn = y4f[ix];                                              \
        if (kk >= NFRM) { gn = 0.f; yn = 0.f; } }
#define KD_REPLAY(gn, yn, i)                                                   \
    {   int kk = k0 + (i);                                                     \
        if (kk < NFRM) o[kk] = fmaf(alpha, sv, yn);                            \
        sv = fmaf(aL, sv, gn); }

__global__ __launch_bounds__(256) void kD_scan_par(
        const float* __restrict__ G, const float* __restrict__ y4f,
        float* __restrict__ out, float alpha, float aL) {
    int id = blockIdx.x * 4 + (threadIdx.x >> 6);   // b * NCH + c
    int lane = threadIdx.x & 63;
    if (id >= NSEQ) return;
    int b = id / NCH;
    int c = id - b * NCH;
    float* o = out + (size_t)id * NFRM;
    int k0 = lane * 4;
    if (c == 0) {
        #pragma unroll
        for (int i = 0; i < 4; ++i) {
            int kk = k0 + i;
            if (kk < NFRM) o[kk] = 0.0f;
        }
        return;
    }
    float g0, g1, g2v, g3, y0, y1, y2v, y3;
    KD_LOAD(g0, y0, 0); KD_LOAD(g1, y1, 1); KD_LOAD(g2v, y2v, 2); KD_LOAD(g3, y3, 3);
    // local inclusive carry
    float e = g0;
    e = fmaf(aL, e, g1);
    e = fmaf(aL, e, g2v);
    e = fmaf(aL, e, g3);
    // Kogge-Stone with factor f = (aL^4)^{2^s}
    float aL2 = aL * aL;
    float f = aL2 * aL2;                     // aL^4
    for (int s = 0; s < 6; ++s) {
        int off = 1 << s;
        float src = __shfl_up(e, off, 64);
        if (lane < off) src = 0.f;
        e = fmaf(f, src, e);
        f = f * f;
    }
    // exclusive shift
    float sv = __shfl_up(e, 1, 64);
    if (lane == 0) sv = 0.f;
    // replay + store
    KD_REPLAY(g0, y0, 0); KD_REPLAY(g1, y1, 1);
    KD_REPLAY(g2v, y2v, 2); KD_REPLAY(g3, y3, 3);
}

// ---------------------------------------------------------------------------
extern "C" void kernel_launch(void* const* d_in, const int* in_sizes, int n_in,
                              void* d_out, int out_size, void* d_ws, size_t ws_size,
                              hipStream_t stream) {
    const float* wav = (const float*)d_in[0];   // (BS, TLEN)
    const float* Bc  = (const float*)d_in[1];   // (NCH, 5)
    const float* Ac  = (const float*)d_in[2];   // (NCH, 5)
    float* out = (float*)d_out;                 // (BS, NCH, NFRM)

    // workspace (floats): D | W | ZW (NH*NSEQ*4 = 4.13 MB each)
    //                     | G | y4f (1.03 MB each) | E (SEG*NSEQ*4 = 413 KB)
    float* D   = (float*)d_ws;
    float* W   = D + (size_t)NH * NSEQ * 4;
    float* ZW  = W + (size_t)NH * NSEQ * 4;
    float* G   = ZW + (size_t)NH * NSEQ * 4;
    float* y4f = G + (size_t)NBK * NCH;
    float* E   = y4f + (size_t)NBK * NCH;

    const float alpha  = (float)exp(-1.0 / 128.0);
    const float beta   = (float)exp(-1.0 / 8.0);
    const float alphaL = (float)exp(-256.0 / 128.0);   // alpha^256 (frame step)

    kA_forced_state<<<KA_EDGE + NT, 128, 0, stream>>>(wav, Bc, Ac, D, W);
    kB1_fold<<<SEG * SGRP, 64, 0, stream>>>(Ac, D, E);
    kB2_carry<<<SGRP, 64, 0, stream>>>(Ac, E);
    kB3_replay<<<SEG * SGRP, 64, 0, stream>>>(Ac, D, W, ZW, E);
    kC_main<<<KC_EDGE + KC_MAIN, 256, 0, stream>>>(wav, Bc, Ac, ZW, G, y4f, beta, alpha);
    kD_scan_par<<<NSEQ / 4, 256, 0, stream>>>(G, y4f, out, alpha, alphaL);
}

// Round 8
// 131.638 us; speedup vs baseline: 1.2983x; 1.0070x over previous
//
#include <hip/hip_runtime.h>
#include <math.h>

// Problem constants (from reference)
#define NCH 129
#define BS 8
#define TLEN 64000
#define CHUNK 256         // state granularity == frame length
#define WARM 64           // kC warm-up length (samples before frame start)
#define NH 250            // TLEN / CHUNK state chunks (== NFRM)
#define TILE 256          // kC tile length (one FULL frame)
#define LFRM 256          // frame stride
#define NFRM 250          // number of frames
#define NSEQ (NCH * BS)   // 1032 sequences
#define NBK (BS * NFRM)   // 2000 (b,frame) cells
#define NT (BS * NH)      // 2000 (b,chunk) items (kernel A)
#define KA_EDGE 8         // ceil(NT/256): kA channel-128 blocks
#define KA_MAIN (NT / 4)  // 500 main blocks (4 chunk-tiles per 256-thr block)
#define KC_EDGE 8         // ceil(NBK/256): kC channel-128 blocks
#define KC_MAIN (NBK / 4) // 500 main blocks (4 frame-tiles per 256-thr block)
#define SEG 25            // kB segments
#define LSEG 10           // chunks per segment (SEG*LSEG == NH)
#define SGRP 17           // ceil(NSEQ/64) sequence groups per segment

// float4 index of state-chunk h, batch b, channel c.  Layout [h][b][c]:
// c fastest -> kA writes and kC reads are coalesced.
#define SEQ4(h, b, c) ((size_t)(h) * NSEQ + (size_t)(b) * NCH + (c))

typedef float f2 __attribute__((ext_vector_type(2)));

__device__ __forceinline__ f2 mk2(float a, float b) { f2 r; r.x = a; r.y = b; return r; }

// Packed fp32 FMA/MUL via VOP3P — one instruction for both lanes of the f2.
// (v_pk_fma_f32 is the only path to the 157 TF fp32 peak; the compiler does
// not emit it for __builtin_elementwise_fma. IEEE-fused, bit-identical to
// scalar v_fma_f32.)
__device__ __forceinline__ f2 fma2(f2 a, f2 b, f2 c) {
    f2 d;
    asm("v_pk_fma_f32 %0, %1, %2, %3" : "=v"(d) : "v"(a), "v"(b), "v"(c));
    return d;
}
__device__ __forceinline__ f2 mul2(f2 a, f2 b) {
    f2 d;
    asm("v_pk_mul_f32 %0, %1, %2" : "=v"(d) : "v"(a), "v"(b));
    return d;
}

__device__ __forceinline__ f2 sig2(f2 v) {
    f2 r;
    r.x = __builtin_amdgcn_rcpf(1.0f + __expf(-v.x));
    r.y = __builtin_amdgcn_rcpf(1.0f + __expf(-v.y));
    return r;
}

// Packed pair-of-chains coefficients. a-coefs stored NEGATED (the asm pk-fma
// cannot fold a neg modifier).
struct C2 { f2 b0, b1, b2, b3, b4, na1, na2, na3, na4; };

__device__ __forceinline__ C2 load_coef2(const float* __restrict__ B,
                                         const float* __restrict__ A,
                                         int cx, int cy) {
    C2 q;
    q.b0 = mk2(B[cx * 5 + 0], B[cy * 5 + 0]);
    q.b1 = mk2(B[cx * 5 + 1], B[cy * 5 + 1]);
    q.b2 = mk2(B[cx * 5 + 2], B[cy * 5 + 2]);
    q.b3 = mk2(B[cx * 5 + 3], B[cy * 5 + 3]);
    q.b4 = mk2(B[cx * 5 + 4], B[cy * 5 + 4]);
    q.na1 = mk2(-A[cx * 5 + 1], -A[cy * 5 + 1]);
    q.na2 = mk2(-A[cx * 5 + 2], -A[cy * 5 + 2]);
    q.na3 = mk2(-A[cx * 5 + 3], -A[cy * 5 + 3]);
    q.na4 = mk2(-A[cx * 5 + 4], -A[cy * 5 + 4]);
    return q;
}

__device__ __forceinline__ f2 iir2_step(const C2& q, float x,
                                        f2& z0, f2& z1, f2& z2, f2& z3) {
    f2 xx = mk2(x, x);
    f2 y = fma2(q.b0, xx, z0);
    z0 = fma2(q.na1, y, fma2(q.b1, xx, z1));
    z1 = fma2(q.na2, y, fma2(q.b2, xx, z2));
    z2 = fma2(q.na3, y, fma2(q.b3, xx, z3));
    z3 = fma2(q.na4, y, mul2(q.b4, xx));
    return y;
}

// Scalar variants (kernel A edge only).
struct Coef { float b0, b1, b2, b3, b4, a1, a2, a3, a4; };
__device__ __forceinline__ Coef load_coef(const float* __restrict__ B,
                                          const float* __restrict__ A, int c) {
    Coef q;
    q.b0 = B[c * 5 + 0]; q.b1 = B[c * 5 + 1]; q.b2 = B[c * 5 + 2];
    q.b3 = B[c * 5 + 3]; q.b4 = B[c * 5 + 4];
    q.a1 = A[c * 5 + 1]; q.a2 = A[c * 5 + 2];
    q.a3 = A[c * 5 + 3]; q.a4 = A[c * 5 + 4];
    return q;
}
__device__ __forceinline__ float iir_step(const Coef& q, float x,
                                          float& z0, float& z1, float& z2, float& z3) {
    float y = fmaf(q.b0, x, z0);
    z0 = fmaf(-q.a1, y, fmaf(q.b1, x, z1));
    z1 = fmaf(-q.a2, y, fmaf(q.b2, x, z2));
    z2 = fmaf(-q.a3, y, fmaf(q.b3, x, z3));
    z3 = fmaf(-q.a4, y, q.b4 * x);
    return y;
}

// step macros for packed chains (coef struct must be named q)
#define ISTEP(xv) { (void)iir2_step(q, (xv), z0, z1, z2, z3); }
#define WSTEP(xv)                                                              \
    { f2 y_ = iir2_step(q, (xv), z0, z1, z2, z3);                              \
      u = fma2(beta2, u, sig2(y_)); }
#define MSTEP(xv)                                                              \
    { f2 y_ = iir2_step(q, (xv), z0, z1, z2, z3);                              \
      u = fma2(beta2, u, sig2(y_));                                            \
      float un_ = __shfl_down(u.x, 1, 64);                                     \
      float y4o_ = fmaxf(u.y - u.x, 0.0f);                                     \
      float y4e_ = fmaxf(pend_un - pend_ub, 0.0f);                             \
      g2 = fma2(alpha2, g2, mk2(y4o_, y4e_));                                  \
      pend_un = un_; pend_ub = u.y; }

// ---- 4x4 matrix helpers over 16 NAMED scalars (no arrays -> no scratch) ----
#define MDECL(X) float X##00, X##01, X##02, X##03, X##10, X##11, X##12, X##13, \
                       X##20, X##21, X##22, X##23, X##30, X##31, X##32, X##33
#define MCOPY(D, S) D##00=S##00; D##01=S##01; D##02=S##02; D##03=S##03;        \
                    D##10=S##10; D##11=S##11; D##12=S##12; D##13=S##13;        \
                    D##20=S##20; D##21=S##21; D##22=S##22; D##23=S##23;        \
                    D##30=S##30; D##31=S##31; D##32=S##32; D##33=S##33
#define MROW(R, X, Y, i)                                                       \
    R##i##0 = fmaf(X##i##0, Y##00, fmaf(X##i##1, Y##10, fmaf(X##i##2, Y##20, X##i##3 * Y##30))); \
    R##i##1 = fmaf(X##i##0, Y##01, fmaf(X##i##1, Y##11, fmaf(X##i##2, Y##21, X##i##3 * Y##31))); \
    R##i##2 = fmaf(X##i##0, Y##02, fmaf(X##i##1, Y##12, fmaf(X##i##2, Y##22, X##i##3 * Y##32))); \
    R##i##3 = fmaf(X##i##0, Y##03, fmaf(X##i##1, Y##13, fmaf(X##i##2, Y##23, X##i##3 * Y##33)))
#define MMUL(R, X, Y) MROW(R, X, Y, 0); MROW(R, X, Y, 1); MROW(R, X, Y, 2); MROW(R, X, Y, 3)
// r (float4) = X * v (float4)
#define MV(r, X, v)                                                            \
    r.x = fmaf(X##00, v.x, fmaf(X##01, v.y, fmaf(X##02, v.z, X##03 * v.w)));   \
    r.y = fmaf(X##10, v.x, fmaf(X##11, v.y, fmaf(X##12, v.z, X##13 * v.w)));   \
    r.z = fmaf(X##20, v.x, fmaf(X##21, v.y, fmaf(X##22, v.z, X##23 * v.w)));   \
    r.w = fmaf(X##30, v.x, fmaf(X##31, v.y, fmaf(X##32, v.z, X##33 * v.w)))
// build companion matrix M and raise to M^(2^NSQ) via NSQ squarings
#define BUILD_MPOW(M1, a1, a2, a3, a4, NSQ)                                    \
    M1##00 = -(a1); M1##01 = 1.f; M1##02 = 0.f; M1##03 = 0.f;                  \
    M1##10 = -(a2); M1##11 = 0.f; M1##12 = 1.f; M1##13 = 0.f;                  \
    M1##20 = -(a3); M1##21 = 0.f; M1##22 = 0.f; M1##23 = 1.f;                  \
    M1##30 = -(a4); M1##31 = 0.f; M1##32 = 0.f; M1##33 = 0.f;                  \
    for (int s_ = 0; s_ < (NSQ); ++s_) { MDECL(T_); MMUL(T_, M1, M1); MCOPY(M1, T_); }

// affine step helper: e = M*e + d
#define AFF_STEP(M, e, d)                                                      \
    {   float4 t_; MV(t_, M, e);                                               \
        e.x = t_.x + d.x; e.y = t_.y + d.y;                                    \
        e.z = t_.z + d.z; e.w = t_.w + d.w; }

// ---------------------------------------------------------------------------
// Kernel A: forced response per (c, b, 256-chunk h) from zero state.
// Writes TWO snapshots per chunk: W[h] = state after 192 samples and
// D[h] = state after 256 samples (the scan increment).
// Blocks [0, KA_EDGE): channel 128 — one (b,h) item per thread, scalar.
// Blocks [KA_EDGE, +KA_MAIN): pair-channel packed main (mirrors kC):
// wave w -> chunk-tile blk*4+w; lane t runs packed chains {2t,2t+1}.
// ---------------------------------------------------------------------------
__global__ __launch_bounds__(256, 8) void kA_forced_state(
        const float* __restrict__ wav, const float* __restrict__ B,
        const float* __restrict__ A, float* __restrict__ D,
        float* __restrict__ W) {
    __shared__ float4 xs4[4 * 64];   // per-wave 64-float4 segments (256 smp)
    int blk = blockIdx.x;
    if (blk < KA_EDGE) {
        int item = blk * 256 + threadIdx.x;
        if (item >= NT) return;
        int b = item / NH;
        int h = item - b * NH;
        const float* xg = wav + (size_t)b * TLEN + (size_t)h * CHUNK;
        Coef q = load_coef(B, A, 128);
        float z0 = 0.f, z1 = 0.f, z2 = 0.f, z3 = 0.f;
        #pragma unroll 4
        for (int j = 0; j < CHUNK - WARM; ++j) {
            (void)iir_step(q, xg[j], z0, z1, z2, z3);
        }
        ((float4*)W)[SEQ4(h, b, 128)] = make_float4(z0, z1, z2, z3);
        #pragma unroll 4
        for (int j = CHUNK - WARM; j < CHUNK; ++j) {
            (void)iir_step(q, xg[j], z0, z1, z2, z3);
        }
        ((float4*)D)[SEQ4(h, b, 128)] = make_float4(z0, z1, z2, z3);
        return;
    }
    // ---- main: wave w handles chunk-tile (blk-KA_EDGE)*4 + w ----
    int wave = threadIdx.x >> 6;
    int t = threadIdx.x & 63;
    int tile = (blk - KA_EDGE) * 4 + wave;   // b * NH + h, < NT
    int b = tile / NH;
    int h = tile - b * NH;
    const float* xg = wav + (size_t)b * TLEN + (size_t)h * CHUNK;
    float4* seg = xs4 + wave * 64;
    seg[t] = ((const float4*)xg)[t];         // 64 lanes x 16B = 256 floats
    __syncthreads();

    int cA = 2 * t, cB = 2 * t + 1;
    C2 q = load_coef2(B, A, cA, cB);
    f2 z0 = mk2(0.f, 0.f), z1 = z0, z2 = z0, z3 = z0;
    for (int g = 0; g < (CHUNK - WARM) / 4; ++g) {   // 192 steps
        float4 xq = seg[g];
        ISTEP(xq.x); ISTEP(xq.y); ISTEP(xq.z); ISTEP(xq.w);
    }
    ((float4*)W)[SEQ4(h, b, cA)] = make_float4(z0.x, z1.x, z2.x, z3.x);
    ((float4*)W)[SEQ4(h, b, cB)] = make_float4(z0.y, z1.y, z2.y, z3.y);
    for (int g = (CHUNK - WARM) / 4; g < CHUNK / 4; ++g) {  // 64 steps
        float4 xq = seg[g];
        ISTEP(xq.x); ISTEP(xq.y); ISTEP(xq.z); ISTEP(xq.w);
    }
    ((float4*)D)[SEQ4(h, b, cA)] = make_float4(z0.x, z1.x, z2.x, z3.x);
    ((float4*)D)[SEQ4(h, b, cB)] = make_float4(z0.y, z1.y, z2.y, z3.y);
}

// ---------------------------------------------------------------------------
// Kernel B (3-pass segmented affine scan over 256-chunks, lane-coalesced).
// kB1: E[seg][s] = fold of segment's 10 D's with M256.
// kB2: serial scan over 25 segment carries with ML = M256^10 (prefetched);
//      overwrites E[seg][s] with the EXCLUSIVE segment-start state.
// kB3: replay 10 chunks per segment; writes ZW[h] = M192*z_in[h] + W[h]
//      (exact state at 256h+192), then advances via M256 and D[h].
// ---------------------------------------------------------------------------
__global__ __launch_bounds__(64) void kB1_fold(
        const float* __restrict__ A, const float* __restrict__ D,
        float* __restrict__ E) {
    int seg = blockIdx.x / SGRP;
    int s = (blockIdx.x % SGRP) * 64 + threadIdx.x;
    if (s >= NSEQ) return;
    int c = s % NCH;
    float a1 = A[c * 5 + 1], a2 = A[c * 5 + 2], a3 = A[c * 5 + 3], a4 = A[c * 5 + 4];
    MDECL(M1); BUILD_MPOW(M1, a1, a2, a3, a4, 8);   // M^256
    const float4* db = (const float4*)D;
    float4 e = make_float4(0.f, 0.f, 0.f, 0.f);
    size_t base = (size_t)seg * LSEG * NSEQ + s;
    #pragma unroll
    for (int i = 0; i < LSEG; ++i) {
        float4 d = db[base + (size_t)i * NSEQ];
        AFF_STEP(M1, e, d);
    }
    ((float4*)E)[(size_t)seg * NSEQ + s] = e;
}

__global__ __launch_bounds__(64) void kB2_carry(
        const float* __restrict__ A, float* __restrict__ E) {
    int s = blockIdx.x * 64 + threadIdx.x;
    if (s >= NSEQ) return;
    int c = s % NCH;
    float a1 = A[c * 5 + 1], a2 = A[c * 5 + 2], a3 = A[c * 5 + 3], a4 = A[c * 5 + 4];
    MDECL(M1); BUILD_MPOW(M1, a1, a2, a3, a4, 8);   // M^256
    // ML = M256^10 = P8 * P2
    MDECL(P2); MMUL(P2, M1, M1);
    MDECL(P4); MMUL(P4, P2, P2);
    MDECL(P8); MMUL(P8, P4, P4);
    MDECL(ML); MMUL(ML, P8, P2);
    float4* E4 = (float4*)E;
    float4 Z = make_float4(0.f, 0.f, 0.f, 0.f);
    float4 Eseg = E4[s];                       // prefetch seg 0
    for (int seg = 0; seg < SEG; ++seg) {
        float4 Enext;
        if (seg + 1 < SEG) Enext = E4[(size_t)(seg + 1) * NSEQ + s];
        else               Enext = Z;
        E4[(size_t)seg * NSEQ + s] = Z;        // exclusive segment-start state
        AFF_STEP(ML, Z, Eseg);
        Eseg = Enext;
    }
}

__global__ __launch_bounds__(64) void kB3_replay(
        const float* __restrict__ A, const float* __restrict__ D,
        const float* __restrict__ W, float* __restrict__ ZW,
        const float* __restrict__ E) {
    int seg = blockIdx.x / SGRP;
    int s = (blockIdx.x % SGRP) * 64 + threadIdx.x;
    if (s >= NSEQ) return;
    int c = s % NCH;
    float a1 = A[c * 5 + 1], a2 = A[c * 5 + 2], a3 = A[c * 5 + 3], a4 = A[c * 5 + 4];
    MDECL(M64); BUILD_MPOW(M64, a1, a2, a3, a4, 6);  // M^64
    MDECL(M128); MMUL(M128, M64, M64);               // M^128
    MDECL(M192); MMUL(M192, M128, M64);              // M^192
    MDECL(M256); MMUL(M256, M128, M128);             // M^256
    const float4* db = (const float4*)D;
    const float4* wb = (const float4*)W;
    float4* zwb = (float4*)ZW;
    float4 z = ((const float4*)E)[(size_t)seg * NSEQ + s];
    int h0 = seg * LSEG;
    #pragma unroll
    for (int i = 0; i < LSEG; ++i) {
        size_t ix = (size_t)(h0 + i) * NSEQ + s;
        float4 d = db[ix];
        float4 w = wb[ix];
        float4 zw; MV(zw, M192, z);
        zw.x += w.x; zw.y += w.y; zw.z += w.z; zw.w += w.w;
        zwb[ix] = zw;                // exact state at sample 256h+192
        AFF_STEP(M256, z, d);        // advance to next chunk boundary
    }
}

// ---------------------------------------------------------------------------
// Kernel C: FULL-FRAME tiles (256 samples), 256-thr blocks (4 tiles/block).
// Tile r covers frame r = samples [256r, 256r+256). Warm-up: 64 WSTEPs over
// [256r-64, 256r) from the EXACT state ZW[r-1] (beta^64 u-truncation).
// Blocks [0, KC_EDGE): channel-128 path, one (b,r) item per thread.
// Blocks [KC_EDGE, +KC_MAIN): pair-channel main, wave w -> tile blk*4+w;
// lane t runs packed chains {2t,2t+1}; shfl consumed one step late.
// ---------------------------------------------------------------------------
__global__ __launch_bounds__(256, 8) void kC_main(
        const float* __restrict__ wav, const float* __restrict__ B,
        const float* __restrict__ A, const float* __restrict__ ZW,
        float* __restrict__ G, float* __restrict__ y4f,
        float beta, float alpha) {
    __shared__ float4 xs4[4 * 80];   // per-wave up to 80-float4 segments
    int blk = blockIdx.x;
    const f2 beta2 = mk2(beta, beta);
    const f2 alpha2 = mk2(alpha, alpha);

    if (blk < KC_EDGE) {
        // ---- edge: channel 128, one (b,r) per thread ----
        int item = blk * 256 + threadIdx.x;
        if (item >= NBK) return;
        int b = item / NFRM;
        int r = item - b * NFRM;
        C2 q = load_coef2(B, A, 127, 128);
        f2 z0 = mk2(0.f, 0.f), z1 = z0, z2 = z0, z3 = z0, u = z0;
        const float* xg;
        if (r > 0) {
            float4 vx = ((const float4*)ZW)[SEQ4(r - 1, b, 127)];
            float4 vy = ((const float4*)ZW)[SEQ4(r - 1, b, 128)];
            z0 = mk2(vx.x, vy.x); z1 = mk2(vx.y, vy.y);
            z2 = mk2(vx.z, vy.z); z3 = mk2(vx.w, vy.w);
            xg = wav + (size_t)b * TLEN + (size_t)r * TILE - WARM;
            #pragma unroll 2
            for (int j = 0; j < WARM; ++j) WSTEP(xg[j]);
            xg += WARM;
        } else {
            xg = wav + (size_t)b * TLEN;
        }
        float g4 = 0.f, yfirst = 0.f;
        #pragma unroll 2
        for (int j = 0; j < TILE; ++j) {
            f2 y_ = iir2_step(q, xg[j], z0, z1, z2, z3);
            u = fma2(beta2, u, sig2(y_));
            float y4 = fmaxf(u.y - u.x, 0.0f);   // ch128 - ch127
            if (j == 0) yfirst = y4;
            g4 = fmaf(alpha, g4, y4);
        }
        size_t idx = ((size_t)b * NFRM + r) * NCH + 128;
        G[idx] = g4;
        y4f[idx] = yfirst;
        return;
    }

    // ---- main: wave w handles frame-tile (blk-KC_EDGE)*4 + w ----
    int wave = threadIdx.x >> 6;
    int t = threadIdx.x & 63;                // lane 0..63
    int tile = (blk - KC_EDGE) * 4 + wave;   // b * NFRM + r, < NBK
    int b = tile / NFRM;
    int r = tile - b * NFRM;
    int n4 = (r > 0) ? 80 : 64;              // (64 warm + 256 main) or 256
    const float* xg = wav + (size_t)b * TLEN +
                      ((r > 0) ? (size_t)r * TILE - WARM : (size_t)0);
    float4* seg = xs4 + wave * 80;
    for (int i = t; i < n4; i += 64) seg[i] = ((const float4*)xg)[i];
    __syncthreads();

    int cA = 2 * t, cB = 2 * t + 1;          // chains (cB <= 127)
    C2 q = load_coef2(B, A, cA, cB);
    f2 z0 = mk2(0.f, 0.f), z1 = z0, z2 = z0, z3 = z0, u = z0;
    int gbase = 0;
    if (r > 0) {
        // coalesced: wave reads c = 0..127 consecutive float4s
        float4 vx = ((const float4*)ZW)[SEQ4(r - 1, b, cA)];
        float4 vy = ((const float4*)ZW)[SEQ4(r - 1, b, cB)];
        z0 = mk2(vx.x, vy.x); z1 = mk2(vx.y, vy.y);
        z2 = mk2(vx.z, vy.z); z3 = mk2(vx.w, vy.w);
        for (int g = 0; g < WARM / 4; ++g) {       // 16 groups = 64 warm steps
            float4 xq = seg[g];
            WSTEP(xq.x); WSTEP(xq.y); WSTEP(xq.z); WSTEP(xq.w);
        }
        gbase = WARM / 4;
    }

    // main 256 steps; pipeline: ge consumes shfl one step late.
    f2 g2;
    float fo, fe, pend_un, pend_ub;
    {   // first group: peel j=0 and j=1
        float4 xq = seg[gbase];
        // j = 0
        f2 y_ = iir2_step(q, xq.x, z0, z1, z2, z3);
        u = fma2(beta2, u, sig2(y_));
        float un_ = __shfl_down(u.x, 1, 64);
        float y4o_ = fmaxf(u.y - u.x, 0.0f);
        fo = y4o_;
        g2 = mk2(y4o_, 0.0f);
        pend_un = un_; pend_ub = u.y;
        // j = 1
        y_ = iir2_step(q, xq.y, z0, z1, z2, z3);
        u = fma2(beta2, u, sig2(y_));
        un_ = __shfl_down(u.x, 1, 64);
        y4o_ = fmaxf(u.y - u.x, 0.0f);
        float y4e_ = fmaxf(pend_un - pend_ub, 0.0f);
        fe = y4e_;                            // y4e at j=0
        g2 = fma2(alpha2, g2, mk2(y4o_, y4e_));
        pend_un = un_; pend_ub = u.y;
        // j = 2, 3
        MSTEP(xq.z); MSTEP(xq.w);
    }
    for (int g = gbase + 1; g < gbase + TILE / 4; ++g) {
        float4 xq = seg[g];
        MSTEP(xq.x); MSTEP(xq.y); MSTEP(xq.z); MSTEP(xq.w);
    }
    // tail: apply the last pending ge term
    float y4e_last = fmaxf(pend_un - pend_ub, 0.0f);
    float go = g2.x;
    float ge = fmaf(alpha, g2.y, y4e_last);

    size_t base = ((size_t)b * NFRM + r) * NCH;
    G[base + cB] = go;             // channel 2t+1 (odd 1..127)
    y4f[base + cB] = fo;
    if (t < 63) {
        G[base + cB + 1] = ge;     // channel 2t+2 (even 2..126)
        y4f[base + cB + 1] = fe;
    }
}

// ---------------------------------------------------------------------------
// Kernel D: PARALLEL alpha-scan per (b,c) — one wave per sequence.
// Lane l owns frames [4l, 4l+4) (256 >= NFRM=250, padded g=0).
//   o[k] = alpha * s_in[k] + y4f[k];  s' = aL*s + G[k]  (full-frame fold).
// Kogge-Stone over lanes with scalar factor (aL^4)^{2^s}.
// ---------------------------------------------------------------------------
#define KD_LOAD(gn, yn, i)                                                     \
    {   int kk = k0 + (i); int kcl = (kk < NFRM) ? kk : (NFRM - 1);            \
        size_t ix = ((size_t)b * NFRM + kcl) * NCH + c;                        \
        gn = G[ix]; yn = y4f[ix];                                              \
        if (kk >= NFRM) { gn = 0.f; yn = 0.f; } }
#define KD_REPLAY(gn, yn, i)                                                   \
    {   int kk = k0 + (i);                                                     \
        if (kk < NFRM) o[kk] = fmaf(alpha, sv, yn);                            \
        sv = fmaf(aL, sv, gn); }

__global__ __launch_bounds__(256) void kD_scan_par(
        const float* __restrict__ G, const float* __restrict__ y4f,
        float* __restrict__ out, float alpha, float aL) {
    int id = blockIdx.x * 4 + (threadIdx.x >> 6);   // b * NCH + c
    int lane = threadIdx.x & 63;
    if (id >= NSEQ) return;
    int b = id / NCH;
    int c = id - b * NCH;
    float* o = out + (size_t)id * NFRM;
    int k0 = lane * 4;
    if (c == 0) {
        #pragma unroll
        for (int i = 0; i < 4; ++i) {
            int kk = k0 + i;
            if (kk < NFRM) o[kk] = 0.0f;
        }
        return;
    }
    float g0, g1, g2v, g3, y0, y1, y2v, y3;
    KD_LOAD(g0, y0, 0); KD_LOAD(g1, y1, 1); KD_LOAD(g2v, y2v, 2); KD_LOAD(g3, y3, 3);
    // local inclusive carry
    float e = g0;
    e = fmaf(aL, e, g1);
    e = fmaf(aL, e, g2v);
    e = fmaf(aL, e, g3);
    // Kogge-Stone with factor f = (aL^4)^{2^s}
    float aL2 = aL * aL;
    float f = aL2 * aL2;                     // aL^4
    for (int s = 0; s < 6; ++s) {
        int off = 1 << s;
        float src = __shfl_up(e, off, 64);
        if (lane < off) src = 0.f;
        e = fmaf(f, src, e);
        f = f * f;
    }
    // exclusive shift
    float sv = __shfl_up(e, 1, 64);
    if (lane == 0) sv = 0.f;
    // replay + store
    KD_REPLAY(g0, y0, 0); KD_REPLAY(g1, y1, 1);
    KD_REPLAY(g2v, y2v, 2); KD_REPLAY(g3, y3, 3);
}

// ---------------------------------------------------------------------------
extern "C" void kernel_launch(void* const* d_in, const int* in_sizes, int n_in,
                              void* d_out, int out_size, void* d_ws, size_t ws_size,
                              hipStream_t stream) {
    const float* wav = (const float*)d_in[0];   // (BS, TLEN)
    const float* Bc  = (const float*)d_in[1];   // (NCH, 5)
    const float* Ac  = (const float*)d_in[2];   // (NCH, 5)
    float* out = (float*)d_out;                 // (BS, NCH, NFRM)

    // workspace (floats): D | W | ZW (NH*NSEQ*4 = 4.13 MB each)
    //                     | G | y4f (1.03 MB each) | E (SEG*NSEQ*4 = 413 KB)
    float* D   = (float*)d_ws;
    float* W   = D + (size_t)NH * NSEQ * 4;
    float* ZW  = W + (size_t)NH * NSEQ * 4;
    float* G   = ZW + (size_t)NH * NSEQ * 4;
    float* y4f = G + (size_t)NBK * NCH;
    float* E   = y4f + (size_t)NBK * NCH;

    const float alpha  = (float)exp(-1.0 / 128.0);
    const float beta   = (float)exp(-1.0 / 8.0);
    const float alphaL = (float)exp(-256.0 / 128.0);   // alpha^256 (frame step)

    kA_forced_state<<<KA_EDGE + KA_MAIN, 256, 0, stream>>>(wav, Bc, Ac, D, W);
    kB1_fold<<<SEG * SGRP, 64, 0, stream>>>(Ac, D, E);
    kB2_carry<<<SGRP, 64, 0, stream>>>(Ac, E);
    kB3_replay<<<SEG * SGRP, 64, 0, stream>>>(Ac, D, W, ZW, E);
    kC_main<<<KC_EDGE + KC_MAIN, 256, 0, stream>>>(wav, Bc, Ac, ZW, G, y4f, beta, alpha);
    kD_scan_par<<<NSEQ / 4, 256, 0, stream>>>(G, y4f, out, alpha, alphaL);
}